// Round 7
// baseline (606.550 us; speedup 1.0000x reference)
//
#include <hip/hip_runtime.h>
#include <hip/hip_fp16.h>

#define N_NODES 100000
#define N_EDGES 3200000
#define NBK 391          // ceil(N_NODES / 256) buckets, 256 nodes each
#define EPB 8192         // edges per block in binning passes
#define NBLK_BIN 391     // ceil(N_EDGES / EPB)

// ==================== common helpers ====================

__device__ __forceinline__ int wave_incl_scan_i(int v) {
  int lane = threadIdx.x & 63;
#pragma unroll
  for (int off = 1; off < 64; off <<= 1) {
    int n = __shfl_up(v, off);
    if (lane >= off) v += n;
  }
  return v;
}

// ==================== CSR build: bucketed counting sort ====================

__global__ __launch_bounds__(256) void bin_hist(const int* __restrict__ tgt,
                                                int* __restrict__ count) {
  __shared__ int hist[NBK];
  int t = threadIdx.x;
  for (int i = t; i < NBK; i += 256) hist[i] = 0;
  __syncthreads();
  int e0 = blockIdx.x * EPB;
  int e1 = min(e0 + EPB, N_EDGES);
  for (int e = e0 + t; e < e1; e += 256) atomicAdd(&hist[tgt[e] >> 8], 1);
  __syncthreads();
  for (int i = t; i < NBK; i += 256) {
    int c = hist[i];
    if (c) atomicAdd(&count[i], c);
  }
}

__global__ __launch_bounds__(512) void bin_scan(const int* __restrict__ count,
                                                int* __restrict__ bktBase,
                                                int* __restrict__ cursor) {
  __shared__ int lds[8];
  int t = threadIdx.x;
  int v = (t < NBK) ? count[t] : 0;
  int inc = wave_incl_scan_i(v);
  int lane = t & 63, wid = t >> 6;
  if (lane == 63) lds[wid] = inc;
  __syncthreads();
  if (t == 0) {
    int run = 0;
#pragma unroll
    for (int i = 0; i < 8; i++) { int c = lds[i]; lds[i] = run; run += c; }
  }
  __syncthreads();
  int ex = inc - v + lds[wid];
  if (t < NBK) { bktBase[t] = ex; cursor[t] = ex; }
  if (t == NBK) bktBase[NBK] = ex;  // == N_EDGES
}

__global__ __launch_bounds__(256) void bin_scatter(const int* __restrict__ src,
                                                   const int* __restrict__ tgt,
                                                   int* __restrict__ cursor,
                                                   unsigned int* __restrict__ binned) {
  __shared__ int hist[NBK];
  __shared__ int lbase[NBK];
  int t = threadIdx.x;
  for (int i = t; i < NBK; i += 256) hist[i] = 0;
  __syncthreads();
  int e0 = blockIdx.x * EPB;
  int e1 = min(e0 + EPB, N_EDGES);
  for (int e = e0 + t; e < e1; e += 256) atomicAdd(&hist[tgt[e] >> 8], 1);
  __syncthreads();
  for (int i = t; i < NBK; i += 256) {
    int c = hist[i];
    lbase[i] = c ? atomicAdd(&cursor[i], c) : 0;
    hist[i] = 0;  // reuse as local cursor
  }
  __syncthreads();
  for (int e = e0 + t; e < e1; e += 256) {
    int tg = tgt[e];
    int bkt = tg >> 8;
    int lo = atomicAdd(&hist[bkt], 1);
    binned[lbase[bkt] + lo] = (unsigned int)src[e] | ((unsigned int)(tg & 255) << 17);
  }
}

__global__ __launch_bounds__(256) void bucket_sort(const unsigned int* __restrict__ binned,
                                                   const int* __restrict__ bktBase,
                                                   int* __restrict__ csr,
                                                   int* __restrict__ offs) {
  __shared__ int deg[256];
  __shared__ int lcur[256];
  __shared__ int wsum[4];
  int b = blockIdx.x;
  int t = threadIdx.x;
  int base = bktBase[b];
  int cnt = bktBase[b + 1] - base;
  deg[t] = 0;
  __syncthreads();
  for (int i = t; i < cnt; i += 256) atomicAdd(&deg[binned[base + i] >> 17], 1);
  __syncthreads();
  int v = deg[t];
  int inc = wave_incl_scan_i(v);
  int lane = t & 63, wid = t >> 6;
  if (lane == 63) wsum[wid] = inc;
  __syncthreads();
  if (t == 0) {
    int run = 0;
#pragma unroll
    for (int i = 0; i < 4; i++) { int c = wsum[i]; wsum[i] = run; run += c; }
  }
  __syncthreads();
  int incl = inc + wsum[wid];
  lcur[t] = base + incl - v;  // exclusive start
  int node = b * 256 + t;
  if (node < N_NODES) offs[node] = base + incl;  // end position
  __syncthreads();
  for (int i = t; i < cnt; i += 256) {
    unsigned int pv = binned[base + i];
    int pos = atomicAdd(&lcur[pv >> 17], 1);
    csr[pos] = (int)(pv & 0x1FFFFu);
  }
}

// ==================== fp16 split conversion ====================

// x [N][32] f32 -> xh0 [N][16] fp16, xh1 [N][16] fp16 (contiguous halves)
__global__ __launch_bounds__(256) void split_half(const float* __restrict__ x,
                                                  __half2* __restrict__ xh0,
                                                  __half2* __restrict__ xh1) {
  int i = blockIdx.x * 256 + threadIdx.x;
  if (i >= N_NODES * 8) return;
  int node = i >> 3, c = i & 7;
  float2 a = reinterpret_cast<const float2*>(x)[node * 16 + c];
  float2 b = reinterpret_cast<const float2*>(x)[node * 16 + 8 + c];
  xh0[node * 8 + c] = __floats2half2_rn(a.x, a.y);
  xh1[node * 8 + c] = __floats2half2_rn(b.x, b.y);
}

// ==================== L2-resident quarter aggregation ====================

// Sum one 16-channel (32B) fp16 slice over each node's in-edges.
// hq: [N][8] half2 slice (3.2MB -> fits per-XCD L2). aggOut: f32, row stride
// ostrideF floats, pre-offset to this slice's column block.
// Wave per node: 8 lanes per row (half2 each), 8 rows per instr, unroll 4.
__global__ __launch_bounds__(256) void agg_pass(
    const __half2* __restrict__ hq, const int* __restrict__ csr,
    const int* __restrict__ offs, float* __restrict__ aggOut, int ostrideF) {
  int node = blockIdx.x * 4 + (threadIdx.x >> 6);
  if (node >= N_NODES) return;
  int lane = threadIdx.x & 63;
  int c = lane & 7, e = lane >> 3;

  int end = offs[node];
  int start = node ? offs[node - 1] : 0;

  float ax = 0.f, ay = 0.f;
  int slot = start + e;
  for (; slot + 24 < end; slot += 32) {
    int s0 = csr[slot], s1 = csr[slot + 8], s2 = csr[slot + 16], s3 = csr[slot + 24];
    float2 f0 = __half22float2(hq[(size_t)s0 * 8 + c]);
    float2 f1 = __half22float2(hq[(size_t)s1 * 8 + c]);
    float2 f2 = __half22float2(hq[(size_t)s2 * 8 + c]);
    float2 f3 = __half22float2(hq[(size_t)s3 * 8 + c]);
    ax += (f0.x + f1.x) + (f2.x + f3.x);
    ay += (f0.y + f1.y) + (f2.y + f3.y);
  }
  for (; slot < end; slot += 8) {
    float2 f = __half22float2(hq[(size_t)csr[slot] * 8 + c]);
    ax += f.x;
    ay += f.y;
  }
  // reduce across the 8 row-phases (lane bits 3..5)
#pragma unroll
  for (int off = 8; off < 64; off <<= 1) {
    ax += __shfl_xor(ax, off);
    ay += __shfl_xor(ay, off);
  }
  if (e == 0)
    reinterpret_cast<float2*>(aggOut + (size_t)node * ostrideF)[c] =
        make_float2(ax, ay);
}

// ==================== matmul + LN kernels (no gathers) ====================

// Layer 1: lane o reads agg1[node][o&31] + x-self; 32-k shfl matmul; LN; ReLU;
// writes h1 quarter arrays (fp16).
__global__ __launch_bounds__(256) void l1_matmul(
    const float* __restrict__ agg1, const __half* __restrict__ xh,  // xh: 2 halves contiguous
    const int* __restrict__ offs, const float* __restrict__ Wl,
    const float* __restrict__ Wr, const float* __restrict__ b,
    const float* __restrict__ g, const float* __restrict__ be,
    __half* __restrict__ h1q) {  // 4 quarters contiguous, each [N][16]
  int node = blockIdx.x * 4 + (threadIdx.x >> 6);
  if (node >= N_NODES) return;
  int o = threadIdx.x & 63;

  int end = offs[node];
  int start = node ? offs[node - 1] : 0;
  float inv = 1.0f / fmaxf((float)(end - start), 1.0f);

  float av = agg1[(size_t)node * 32 + (o & 31)];
  float xv = __half2float(
      xh[(size_t)((o >> 4) & 1) * (N_NODES * 16) + (size_t)node * 16 + (o & 15)]);

  float acc = b[o];
#pragma unroll
  for (int k = 0; k < 32; k++) {
    float ak = __shfl(av, k);
    float xk = __shfl(xv, k);
    acc = fmaf(ak * inv, Wl[k * 64 + o], acc);
    acc = fmaf(xk, Wr[k * 64 + o], acc);
  }

  float s = acc;
#pragma unroll
  for (int off = 32; off; off >>= 1) s += __shfl_xor(s, off);
  float mu = s * (1.0f / 64.0f);
  float d = acc - mu;
  float v2 = d * d;
#pragma unroll
  for (int off = 32; off; off >>= 1) v2 += __shfl_xor(v2, off);
  float hv = fmaxf(d * rsqrtf(v2 * (1.0f / 64.0f) + 1e-5f) * g[o] + be[o], 0.0f);
  h1q[(size_t)(o >> 4) * (N_NODES * 16) + (size_t)node * 16 + (o & 15)] =
      __float2half(hv);
}

// Layer 2 + fused layer-3 node part: lane o reads agg2[node][o] + h1-self;
// 64-k shfl matmul; LN; ReLU; h2 stays in regs; epilogue computes
// y3 = h2 @ W_l3 and out_self = h2 @ W_r3 + b3.
__global__ __launch_bounds__(256) void l2_matmul(
    const float* __restrict__ agg2, const __half* __restrict__ h1q,
    const int* __restrict__ offs, const float* __restrict__ Wl,
    const float* __restrict__ Wr, const float* __restrict__ b,
    const float* __restrict__ g, const float* __restrict__ be,
    const float* __restrict__ Wl3, const float* __restrict__ Wr3,
    const float* __restrict__ b3, float* __restrict__ y3,
    float* __restrict__ out) {
  int node = blockIdx.x * 4 + (threadIdx.x >> 6);
  if (node >= N_NODES) return;
  int o = threadIdx.x & 63;

  int end = offs[node];
  int start = node ? offs[node - 1] : 0;
  float inv = 1.0f / fmaxf((float)(end - start), 1.0f);

  float av = agg2[(size_t)node * 64 + o];
  float hv = __half2float(
      h1q[(size_t)(o >> 4) * (N_NODES * 16) + (size_t)node * 16 + (o & 15)]);

  float acc = b[o];
#pragma unroll
  for (int k = 0; k < 64; k++) {
    float ak = __shfl(av, k);
    float hk = __shfl(hv, k);
    acc = fmaf(ak * inv, Wl[k * 64 + o], acc);
    acc = fmaf(hk, Wr[k * 64 + o], acc);
  }

  float s = acc;
#pragma unroll
  for (int off = 32; off; off >>= 1) s += __shfl_xor(s, off);
  float mu = s * (1.0f / 64.0f);
  float d = acc - mu;
  float v2 = d * d;
#pragma unroll
  for (int off = 32; off; off >>= 1) v2 += __shfl_xor(v2, off);
  float h2v = fmaxf(d * rsqrtf(v2 * (1.0f / 64.0f) + 1e-5f) * g[o] + be[o], 0.0f);

  // fused layer-3 node part: lane o holds h2[o]
  float t0 = h2v * Wl3[o * 2 + 0];
  float t1 = h2v * Wl3[o * 2 + 1];
  float t2 = h2v * Wr3[o * 2 + 0];
  float t3 = h2v * Wr3[o * 2 + 1];
#pragma unroll
  for (int off = 32; off; off >>= 1) {
    t0 += __shfl_xor(t0, off);
    t1 += __shfl_xor(t1, off);
    t2 += __shfl_xor(t2, off);
    t3 += __shfl_xor(t3, off);
  }
  if (o == 0) {
    reinterpret_cast<float2*>(y3)[node] = make_float2(t0, t1);
    reinterpret_cast<float2*>(out)[node] = make_float2(t2 + b3[0], t3 + b3[1]);
  }
}

// Layer 3 gather: wave per node, edges strided across lanes, shfl reduce.
// y3 is 800KB -> L2-resident.
__global__ __launch_bounds__(256) void gather3(
    const float* __restrict__ y, const int* __restrict__ csr,
    const int* __restrict__ offs, float* __restrict__ out) {
  int node = blockIdx.x * 4 + (threadIdx.x >> 6);
  if (node >= N_NODES) return;
  int lane = threadIdx.x & 63;

  int end = offs[node];
  int start = node ? offs[node - 1] : 0;
  float inv = 1.0f / fmaxf((float)(end - start), 1.0f);

  float s0 = 0.f, s1 = 0.f;
  for (int slot = start + lane; slot < end; slot += 64) {
    float2 v = reinterpret_cast<const float2*>(y)[csr[slot]];
    s0 += v.x;
    s1 += v.y;
  }
#pragma unroll
  for (int off = 32; off; off >>= 1) {
    s0 += __shfl_xor(s0, off);
    s1 += __shfl_xor(s1, off);
  }
  if (lane == 0) {
    out[(size_t)node * 2 + 0] += s0 * inv;
    out[(size_t)node * 2 + 1] += s1 * inv;
  }
}

// ==================== launch ====================

extern "C" void kernel_launch(void* const* d_in, const int* in_sizes, int n_in,
                              void* d_out, int out_size, void* d_ws, size_t ws_size,
                              hipStream_t stream) {
  const float* x = (const float*)d_in[0];
  const int* ei = (const int*)d_in[1];
  const int* src = ei;
  const int* tgt = ei + N_EDGES;
  const float* Wl1 = (const float*)d_in[2];
  const float* Wr1 = (const float*)d_in[3];
  const float* b1 = (const float*)d_in[4];
  const float* g1 = (const float*)d_in[5];
  const float* be1 = (const float*)d_in[6];
  const float* Wl2 = (const float*)d_in[7];
  const float* Wr2 = (const float*)d_in[8];
  const float* b2 = (const float*)d_in[9];
  const float* g2 = (const float*)d_in[10];
  const float* be2 = (const float*)d_in[11];
  const float* Wl3 = (const float*)d_in[12];
  const float* Wr3 = (const float*)d_in[13];
  const float* b3 = (const float*)d_in[14];
  float* out = (float*)d_out;
  char* ws = (char*)d_ws;

  // ---- workspace layout (~64.5 MB) ----
  size_t p = 0;
  auto carve = [&](size_t bytes) {
    size_t r = p;
    p += (bytes + 255) & ~(size_t)255;
    return r;
  };
  size_t count_off = carve((size_t)NBK * 4);
  size_t base_off = carve((size_t)(NBK + 1) * 4);
  size_t cursor_off = carve((size_t)NBK * 4);
  size_t offs_off = carve((size_t)N_NODES * 4);
  size_t csr_off = carve((size_t)N_EDGES * 4);
  size_t r1_off = carve((size_t)N_EDGES * 4);        // binned; later xh(6.4M)+y3(0.8M)
  size_t agg_off = carve((size_t)N_NODES * 64 * 4);  // agg1 (first half) then agg2
  size_t h1_off = carve((size_t)N_NODES * 64 * 2);   // h1 quarters contiguous

  int* count = (int*)(ws + count_off);
  int* bktBase = (int*)(ws + base_off);
  int* cursor = (int*)(ws + cursor_off);
  int* offs = (int*)(ws + offs_off);
  int* csr = (int*)(ws + csr_off);
  unsigned int* binned = (unsigned int*)(ws + r1_off);
  __half* xh = (__half*)(ws + r1_off);                       // 2 halves, 3.2MB each
  float* y3 = (float*)(ws + r1_off + (size_t)N_NODES * 32 * 2);  // after xh (6.4MB)
  float* agg = (float*)(ws + agg_off);
  __half* h1q = (__half*)(ws + h1_off);

  const int NODE_BLOCKS = (N_NODES + 3) / 4;

  // ---- CSR build ----
  hipMemsetAsync(count, 0, (size_t)NBK * 4, stream);
  bin_hist<<<NBLK_BIN, 256, 0, stream>>>(tgt, count);
  bin_scan<<<1, 512, 0, stream>>>(count, bktBase, cursor);
  bin_scatter<<<NBLK_BIN, 256, 0, stream>>>(src, tgt, cursor, binned);
  bucket_sort<<<NBK, 256, 0, stream>>>(binned, bktBase, csr, offs);

  // ---- fp16 split (binned dead now; xh aliases it) ----
  split_half<<<(N_NODES * 8 + 255) / 256, 256, 0, stream>>>(
      x, (__half2*)xh, (__half2*)(xh + (size_t)N_NODES * 16));

  // ---- layer 1: 2 L2-resident agg passes + matmul ----
  agg_pass<<<NODE_BLOCKS, 256, 0, stream>>>(
      (const __half2*)xh, csr, offs, agg, 32);
  agg_pass<<<NODE_BLOCKS, 256, 0, stream>>>(
      (const __half2*)(xh + (size_t)N_NODES * 16), csr, offs, agg + 16, 32);
  l1_matmul<<<NODE_BLOCKS, 256, 0, stream>>>(
      agg, xh, offs, Wl1, Wr1, b1, g1, be1, h1q);

  // ---- layer 2: 4 L2-resident agg passes + matmul (+fused layer-3 node part) ----
  for (int q = 0; q < 4; q++) {
    agg_pass<<<NODE_BLOCKS, 256, 0, stream>>>(
        (const __half2*)(h1q + (size_t)q * N_NODES * 16), csr, offs,
        agg + q * 16, 64);
  }
  l2_matmul<<<NODE_BLOCKS, 256, 0, stream>>>(
      agg, h1q, offs, Wl2, Wr2, b2, g2, be2, Wl3, Wr3, b3, y3, out);

  // ---- layer 3 gather ----
  gather3<<<NODE_BLOCKS, 256, 0, stream>>>(y3, csr, offs, out);
}

// Round 8
// 591.671 us; speedup vs baseline: 1.0251x; 1.0251x over previous
//
#include <hip/hip_runtime.h>
#include <hip/hip_fp16.h>

#define N_NODES 100000
#define N_EDGES 3200000
#define NBK 391          // ceil(N_NODES / 256) buckets, 256 nodes each
#define EPB 8192         // edges per block in binning passes
#define NBLK_BIN 391     // ceil(N_EDGES / EPB)
#define GRID_L 1024      // persistent-ish grid for fused layer kernels

// ==================== common helpers ====================

__device__ __forceinline__ int wave_incl_scan_i(int v) {
  int lane = threadIdx.x & 63;
#pragma unroll
  for (int off = 1; off < 64; off <<= 1) {
    int n = __shfl_up(v, off);
    if (lane >= off) v += n;
  }
  return v;
}

// ==================== CSR build: bucketed counting sort ====================

__global__ __launch_bounds__(256) void bin_hist(const int* __restrict__ tgt,
                                                int* __restrict__ count) {
  __shared__ int hist[NBK];
  int t = threadIdx.x;
  for (int i = t; i < NBK; i += 256) hist[i] = 0;
  __syncthreads();
  int e0 = blockIdx.x * EPB;
  int e1 = min(e0 + EPB, N_EDGES);
  for (int e = e0 + t; e < e1; e += 256) atomicAdd(&hist[tgt[e] >> 8], 1);
  __syncthreads();
  for (int i = t; i < NBK; i += 256) {
    int c = hist[i];
    if (c) atomicAdd(&count[i], c);
  }
}

__global__ __launch_bounds__(512) void bin_scan(const int* __restrict__ count,
                                                int* __restrict__ bktBase,
                                                int* __restrict__ cursor) {
  __shared__ int lds[8];
  int t = threadIdx.x;
  int v = (t < NBK) ? count[t] : 0;
  int inc = wave_incl_scan_i(v);
  int lane = t & 63, wid = t >> 6;
  if (lane == 63) lds[wid] = inc;
  __syncthreads();
  if (t == 0) {
    int run = 0;
#pragma unroll
    for (int i = 0; i < 8; i++) { int c = lds[i]; lds[i] = run; run += c; }
  }
  __syncthreads();
  int ex = inc - v + lds[wid];
  if (t < NBK) { bktBase[t] = ex; cursor[t] = ex; }
  if (t == NBK) bktBase[NBK] = ex;  // == N_EDGES
}

__global__ __launch_bounds__(256) void bin_scatter(const int* __restrict__ src,
                                                   const int* __restrict__ tgt,
                                                   int* __restrict__ cursor,
                                                   unsigned int* __restrict__ binned) {
  __shared__ int hist[NBK];
  __shared__ int lbase[NBK];
  int t = threadIdx.x;
  for (int i = t; i < NBK; i += 256) hist[i] = 0;
  __syncthreads();
  int e0 = blockIdx.x * EPB;
  int e1 = min(e0 + EPB, N_EDGES);
  for (int e = e0 + t; e < e1; e += 256) atomicAdd(&hist[tgt[e] >> 8], 1);
  __syncthreads();
  for (int i = t; i < NBK; i += 256) {
    int c = hist[i];
    lbase[i] = c ? atomicAdd(&cursor[i], c) : 0;
    hist[i] = 0;  // reuse as local cursor
  }
  __syncthreads();
  for (int e = e0 + t; e < e1; e += 256) {
    int tg = tgt[e];
    int bkt = tg >> 8;
    int lo = atomicAdd(&hist[bkt], 1);
    binned[lbase[bkt] + lo] = (unsigned int)src[e] | ((unsigned int)(tg & 255) << 17);
  }
}

__global__ __launch_bounds__(256) void bucket_sort(const unsigned int* __restrict__ binned,
                                                   const int* __restrict__ bktBase,
                                                   int* __restrict__ csr,
                                                   int* __restrict__ offs) {
  __shared__ int deg[256];
  __shared__ int lcur[256];
  __shared__ int wsum[4];
  int b = blockIdx.x;
  int t = threadIdx.x;
  int base = bktBase[b];
  int cnt = bktBase[b + 1] - base;
  deg[t] = 0;
  __syncthreads();
  for (int i = t; i < cnt; i += 256) atomicAdd(&deg[binned[base + i] >> 17], 1);
  __syncthreads();
  int v = deg[t];
  int inc = wave_incl_scan_i(v);
  int lane = t & 63, wid = t >> 6;
  if (lane == 63) wsum[wid] = inc;
  __syncthreads();
  if (t == 0) {
    int run = 0;
#pragma unroll
    for (int i = 0; i < 4; i++) { int c = wsum[i]; wsum[i] = run; run += c; }
  }
  __syncthreads();
  int incl = inc + wsum[wid];
  lcur[t] = base + incl - v;  // exclusive start
  int node = b * 256 + t;
  if (node < N_NODES) offs[node] = base + incl;  // end position
  __syncthreads();
  for (int i = t; i < cnt; i += 256) {
    unsigned int pv = binned[base + i];
    int pos = atomicAdd(&lcur[pv >> 17], 1);
    csr[pos] = (int)(pv & 0x1FFFFu);
  }
}

// ==================== fp16 conversion ====================

__global__ __launch_bounds__(256) void to_half2(const float* __restrict__ in,
                                                __half2* __restrict__ out, int n2) {
  int i = blockIdx.x * 256 + threadIdx.x;
  if (i >= n2) return;
  float2 v = reinterpret_cast<const float2*>(in)[i];
  out[i] = __floats2half2_rn(v.x, v.y);
}

// ==================== fused layers (R5 gather + LDS weights + persistent) ====

// Layer 1: wave per node (grid-stride). x fp16 (16 half2/row). Quarter-wave
// (16 lanes) per row, 4 edges/stride, unroll 4 -> 16 rows in flight.
// Wl1/Wr1 (16KB) staged in LDS once per block.
__global__ __launch_bounds__(256) void layer1_fused(
    const __half2* __restrict__ xh, const int* __restrict__ csr,
    const int* __restrict__ offs, const float* __restrict__ Wl,
    const float* __restrict__ Wr, const float* __restrict__ b,
    const float* __restrict__ g, const float* __restrict__ be,
    __half* __restrict__ h1) {
  __shared__ float sW[2 * 32 * 64];  // sWl | sWr, 16KB
  for (int i = threadIdx.x; i < 1024; i += 256) {
    float4 v = (i < 512) ? reinterpret_cast<const float4*>(Wl)[i]
                         : reinterpret_cast<const float4*>(Wr)[i - 512];
    reinterpret_cast<float4*>(sW)[i] = v;
  }
  __syncthreads();
  const float* sWl = sW;
  const float* sWr = sW + 2048;

  int wid = threadIdx.x >> 6;
  int lane = threadIdx.x & 63;
  int c = lane & 15, slot4 = lane >> 4;

  for (int node = blockIdx.x * 4 + wid; node < N_NODES; node += GRID_L * 4) {
    int end = offs[node];
    int start = node ? offs[node - 1] : 0;
    float inv = 1.0f / fmaxf((float)(end - start), 1.0f);

    float ax = 0.0f, ay = 0.0f;
    int slot = start + slot4;
    for (; slot + 12 < end; slot += 16) {
      int s0 = csr[slot], s1 = csr[slot + 4], s2 = csr[slot + 8], s3 = csr[slot + 12];
      float2 f0 = __half22float2(xh[(size_t)s0 * 16 + c]);
      float2 f1 = __half22float2(xh[(size_t)s1 * 16 + c]);
      float2 f2 = __half22float2(xh[(size_t)s2 * 16 + c]);
      float2 f3 = __half22float2(xh[(size_t)s3 * 16 + c]);
      ax += (f0.x + f1.x) + (f2.x + f3.x);
      ay += (f0.y + f1.y) + (f2.y + f3.y);
    }
    for (; slot < end; slot += 4) {
      float2 f = __half22float2(xh[(size_t)csr[slot] * 16 + c]);
      ax += f.x;
      ay += f.y;
    }
    ax += __shfl_xor(ax, 16); ay += __shfl_xor(ay, 16);
    ax += __shfl_xor(ax, 32); ay += __shfl_xor(ay, 32);

    float2 xs = __half22float2(xh[(size_t)node * 16 + c]);

    int o = lane;
    float accO = b[o];
#pragma unroll
    for (int k = 0; k < 32; k++) {
      float ak = __shfl((k & 1) ? ay : ax, k >> 1);
      float xk = __shfl((k & 1) ? xs.y : xs.x, k >> 1);
      accO = fmaf(ak * inv, sWl[k * 64 + o], accO);
      accO = fmaf(xk, sWr[k * 64 + o], accO);
    }

    // LayerNorm over 64 lanes + ReLU
    float s = accO;
#pragma unroll
    for (int off = 32; off; off >>= 1) s += __shfl_xor(s, off);
    float mu = s * (1.0f / 64.0f);
    float d = accO - mu;
    float v2 = d * d;
#pragma unroll
    for (int off = 32; off; off >>= 1) v2 += __shfl_xor(v2, off);
    float o2 = d * rsqrtf(v2 * (1.0f / 64.0f) + 1e-5f) * g[o] + be[o];
    h1[(size_t)node * 64 + o] = __float2half(fmaxf(o2, 0.0f));
  }
}

// Layer 2 (+ fused layer-3 node part): wave per node (grid-stride). h1 fp16
// (32 half2/row). Half-wave per row, 2 edges/stride, unroll 4 -> 8 rows in
// flight. Wl2/Wr2 (32KB) staged in LDS once per block. Epilogue keeps h2 in
// registers: y3 = h2 @ W_l3, out_self = h2 @ W_r3 + b3.
__global__ __launch_bounds__(256) void layer2_fused(
    const __half2* __restrict__ h1q, const int* __restrict__ csr,
    const int* __restrict__ offs, const float* __restrict__ Wl,
    const float* __restrict__ Wr, const float* __restrict__ b,
    const float* __restrict__ g, const float* __restrict__ be,
    const float* __restrict__ Wl3, const float* __restrict__ Wr3,
    const float* __restrict__ b3, float* __restrict__ y3,
    float* __restrict__ out) {
  __shared__ float sW[2 * 64 * 64];  // sWl | sWr, 32KB
  for (int i = threadIdx.x; i < 2048; i += 256) {
    float4 v = (i < 1024) ? reinterpret_cast<const float4*>(Wl)[i]
                          : reinterpret_cast<const float4*>(Wr)[i - 1024];
    reinterpret_cast<float4*>(sW)[i] = v;
  }
  __syncthreads();
  const float* sWl = sW;
  const float* sWr = sW + 4096;

  int wid = threadIdx.x >> 6;
  int lane = threadIdx.x & 63;
  int c = lane & 31, half = lane >> 5;

  for (int node = blockIdx.x * 4 + wid; node < N_NODES; node += GRID_L * 4) {
    int end = offs[node];
    int start = node ? offs[node - 1] : 0;
    float inv = 1.0f / fmaxf((float)(end - start), 1.0f);

    float ax = 0.0f, ay = 0.0f;
    int slot = start + half;
    for (; slot + 6 < end; slot += 8) {
      int s0 = csr[slot], s1 = csr[slot + 2], s2 = csr[slot + 4], s3 = csr[slot + 6];
      float2 f0 = __half22float2(h1q[(size_t)s0 * 32 + c]);
      float2 f1 = __half22float2(h1q[(size_t)s1 * 32 + c]);
      float2 f2 = __half22float2(h1q[(size_t)s2 * 32 + c]);
      float2 f3 = __half22float2(h1q[(size_t)s3 * 32 + c]);
      ax += (f0.x + f1.x) + (f2.x + f3.x);
      ay += (f0.y + f1.y) + (f2.y + f3.y);
    }
    for (; slot < end; slot += 2) {
      float2 f = __half22float2(h1q[(size_t)csr[slot] * 32 + c]);
      ax += f.x;
      ay += f.y;
    }
    ax += __shfl_xor(ax, 32);
    ay += __shfl_xor(ay, 32);

    float2 hs = __half22float2(h1q[(size_t)node * 32 + c]);

    int o = lane;
    float accO = b[o];
#pragma unroll
    for (int k = 0; k < 64; k++) {
      float ak = __shfl((k & 1) ? ay : ax, k >> 1);
      float hk = __shfl((k & 1) ? hs.y : hs.x, k >> 1);
      accO = fmaf(ak * inv, sWl[k * 64 + o], accO);
      accO = fmaf(hk, sWr[k * 64 + o], accO);
    }

    float s = accO;
#pragma unroll
    for (int off = 32; off; off >>= 1) s += __shfl_xor(s, off);
    float mu = s * (1.0f / 64.0f);
    float d = accO - mu;
    float v2 = d * d;
#pragma unroll
    for (int off = 32; off; off >>= 1) v2 += __shfl_xor(v2, off);
    float h2v = fmaxf(d * rsqrtf(v2 * (1.0f / 64.0f) + 1e-5f) * g[o] + be[o], 0.0f);

    // fused layer-3 node part: lane o holds h2[o]
    float t0 = h2v * Wl3[o * 2 + 0];
    float t1 = h2v * Wl3[o * 2 + 1];
    float t2 = h2v * Wr3[o * 2 + 0];
    float t3 = h2v * Wr3[o * 2 + 1];
#pragma unroll
    for (int off = 32; off; off >>= 1) {
      t0 += __shfl_xor(t0, off);
      t1 += __shfl_xor(t1, off);
      t2 += __shfl_xor(t2, off);
      t3 += __shfl_xor(t3, off);
    }
    if (lane == 0) {
      reinterpret_cast<float2*>(y3)[node] = make_float2(t0, t1);
      reinterpret_cast<float2*>(out)[node] = make_float2(t2 + b3[0], t3 + b3[1]);
    }
  }
}

// Layer 3 gather: wave per node, edges strided across lanes, shfl reduce.
// y3 is 800KB -> cache-resident.
__global__ __launch_bounds__(256) void gather3(
    const float* __restrict__ y, const int* __restrict__ csr,
    const int* __restrict__ offs, float* __restrict__ out) {
  int node = blockIdx.x * 4 + (threadIdx.x >> 6);
  if (node >= N_NODES) return;
  int lane = threadIdx.x & 63;

  int end = offs[node];
  int start = node ? offs[node - 1] : 0;
  float inv = 1.0f / fmaxf((float)(end - start), 1.0f);

  float s0 = 0.f, s1 = 0.f;
  for (int slot = start + lane; slot < end; slot += 64) {
    float2 v = reinterpret_cast<const float2*>(y)[csr[slot]];
    s0 += v.x;
    s1 += v.y;
  }
#pragma unroll
  for (int off = 32; off; off >>= 1) {
    s0 += __shfl_xor(s0, off);
    s1 += __shfl_xor(s1, off);
  }
  if (lane == 0) {
    out[(size_t)node * 2 + 0] += s0 * inv;
    out[(size_t)node * 2 + 1] += s1 * inv;
  }
}

// ==================== launch ====================

extern "C" void kernel_launch(void* const* d_in, const int* in_sizes, int n_in,
                              void* d_out, int out_size, void* d_ws, size_t ws_size,
                              hipStream_t stream) {
  const float* x = (const float*)d_in[0];
  const int* ei = (const int*)d_in[1];
  const int* src = ei;
  const int* tgt = ei + N_EDGES;
  const float* Wl1 = (const float*)d_in[2];
  const float* Wr1 = (const float*)d_in[3];
  const float* b1 = (const float*)d_in[4];
  const float* g1 = (const float*)d_in[5];
  const float* be1 = (const float*)d_in[6];
  const float* Wl2 = (const float*)d_in[7];
  const float* Wr2 = (const float*)d_in[8];
  const float* b2 = (const float*)d_in[9];
  const float* g2 = (const float*)d_in[10];
  const float* be2 = (const float*)d_in[11];
  const float* Wl3 = (const float*)d_in[12];
  const float* Wr3 = (const float*)d_in[13];
  const float* b3 = (const float*)d_in[14];
  float* out = (float*)d_out;
  char* ws = (char*)d_ws;

  // ---- workspace layout (~33 MB) ----
  size_t p = 0;
  auto carve = [&](size_t bytes) {
    size_t r = p;
    p += (bytes + 255) & ~(size_t)255;
    return r;
  };
  size_t count_off = carve((size_t)NBK * 4);
  size_t base_off = carve((size_t)(NBK + 1) * 4);
  size_t cursor_off = carve((size_t)NBK * 4);
  size_t offs_off = carve((size_t)N_NODES * 4);
  size_t csr_off = carve((size_t)N_EDGES * 4);
  size_t xh_off = carve((size_t)N_NODES * 32 * 2);  // x fp16; later y3 (800KB)
  size_t h1_off = carve((size_t)N_NODES * 64 * 2);  // h1 fp16; binned aliases (12.8MB)

  int* count = (int*)(ws + count_off);
  int* bktBase = (int*)(ws + base_off);
  int* cursor = (int*)(ws + cursor_off);
  int* offs = (int*)(ws + offs_off);
  int* csr = (int*)(ws + csr_off);
  __half2* xh = (__half2*)(ws + xh_off);
  __half* h1 = (__half*)(ws + h1_off);
  unsigned int* binned = (unsigned int*)h1;  // dead before h1 is written

  hipMemsetAsync(count, 0, (size_t)NBK * 4, stream);
  bin_hist<<<NBLK_BIN, 256, 0, stream>>>(tgt, count);
  bin_scan<<<1, 512, 0, stream>>>(count, bktBase, cursor);
  bin_scatter<<<NBLK_BIN, 256, 0, stream>>>(src, tgt, cursor, binned);
  bucket_sort<<<NBK, 256, 0, stream>>>(binned, bktBase, csr, offs);

  to_half2<<<(N_NODES * 16 + 255) / 256, 256, 0, stream>>>(x, xh, N_NODES * 16);

  layer1_fused<<<GRID_L, 256, 0, stream>>>(
      xh, csr, offs, Wl1, Wr1, b1, g1, be1, h1);

  float* y3 = (float*)xh;  // xh dead after layer1; reuse (800KB)
  layer2_fused<<<GRID_L, 256, 0, stream>>>(
      (const __half2*)h1, csr, offs, Wl2, Wr2, b2, g2, be2, Wl3, Wr3, b3, y3, out);

  gather3<<<(N_NODES + 3) / 4, 256, 0, stream>>>(y3, csr, offs, out);
}

// Round 9
// 390.242 us; speedup vs baseline: 1.5543x; 1.5162x over previous
//
#include <hip/hip_runtime.h>
#include <hip/hip_fp16.h>

#define N_NODES 100000
#define N_EDGES 3200000
#define NBK 391          // ceil(N_NODES / 256) buckets, 256 nodes each
#define EPB 8192         // edges per block in binning passes
#define NBLK_BIN 391     // ceil(N_EDGES / EPB)

// ==================== common helpers ====================

__device__ __forceinline__ int wave_incl_scan_i(int v) {
  int lane = threadIdx.x & 63;
#pragma unroll
  for (int off = 1; off < 64; off <<= 1) {
    int n = __shfl_up(v, off);
    if (lane >= off) v += n;
  }
  return v;
}

// ==================== CSR build: bucketed counting sort ====================

// Pass A: per-bucket edge counts; also saves this block's histogram for reuse.
__global__ __launch_bounds__(256) void bin_hist(const int* __restrict__ tgt,
                                                int* __restrict__ count,
                                                int* __restrict__ blockHist) {
  __shared__ int hist[NBK];
  int t = threadIdx.x;
  for (int i = t; i < NBK; i += 256) hist[i] = 0;
  __syncthreads();
  int e0 = blockIdx.x * EPB;
  int e1 = min(e0 + EPB, N_EDGES);
  for (int e = e0 + t; e < e1; e += 256) atomicAdd(&hist[tgt[e] >> 8], 1);
  __syncthreads();
  int* bh = blockHist + (size_t)blockIdx.x * NBK;
  for (int i = t; i < NBK; i += 256) {
    int c = hist[i];
    bh[i] = c;
    if (c) atomicAdd(&count[i], c);
  }
}

__global__ __launch_bounds__(512) void bin_scan(const int* __restrict__ count,
                                                int* __restrict__ bktBase,
                                                int* __restrict__ cursor) {
  __shared__ int lds[8];
  int t = threadIdx.x;
  int v = (t < NBK) ? count[t] : 0;
  int inc = wave_incl_scan_i(v);
  int lane = t & 63, wid = t >> 6;
  if (lane == 63) lds[wid] = inc;
  __syncthreads();
  if (t == 0) {
    int run = 0;
#pragma unroll
    for (int i = 0; i < 8; i++) { int c = lds[i]; lds[i] = run; run += c; }
  }
  __syncthreads();
  int ex = inc - v + lds[wid];
  if (t < NBK) { bktBase[t] = ex; cursor[t] = ex; }
  if (t == NBK) bktBase[NBK] = ex;  // == N_EDGES
}

// Pass B: scatter packed (src | tgtLocal<<17) into bucket regions, reusing
// the saved per-block histogram (no recount).
__global__ __launch_bounds__(256) void bin_scatter(const int* __restrict__ src,
                                                   const int* __restrict__ tgt,
                                                   const int* __restrict__ blockHist,
                                                   int* __restrict__ cursor,
                                                   unsigned int* __restrict__ binned) {
  __shared__ int hist[NBK];
  __shared__ int lbase[NBK];
  int t = threadIdx.x;
  const int* bh = blockHist + (size_t)blockIdx.x * NBK;
  for (int i = t; i < NBK; i += 256) {
    int c = bh[i];
    lbase[i] = c ? atomicAdd(&cursor[i], c) : 0;
    hist[i] = 0;  // local cursor
  }
  __syncthreads();
  int e0 = blockIdx.x * EPB;
  int e1 = min(e0 + EPB, N_EDGES);
  for (int e = e0 + t; e < e1; e += 256) {
    int tg = tgt[e];
    int bkt = tg >> 8;
    int lo = atomicAdd(&hist[bkt], 1);
    binned[lbase[bkt] + lo] = (unsigned int)src[e] | ((unsigned int)(tg & 255) << 17);
  }
}

__global__ __launch_bounds__(256) void bucket_sort(const unsigned int* __restrict__ binned,
                                                   const int* __restrict__ bktBase,
                                                   int* __restrict__ csr,
                                                   int* __restrict__ offs) {
  __shared__ int deg[256];
  __shared__ int lcur[256];
  __shared__ int wsum[4];
  int b = blockIdx.x;
  int t = threadIdx.x;
  int base = bktBase[b];
  int cnt = bktBase[b + 1] - base;
  deg[t] = 0;
  __syncthreads();
  for (int i = t; i < cnt; i += 256) atomicAdd(&deg[binned[base + i] >> 17], 1);
  __syncthreads();
  int v = deg[t];
  int inc = wave_incl_scan_i(v);
  int lane = t & 63, wid = t >> 6;
  if (lane == 63) wsum[wid] = inc;
  __syncthreads();
  if (t == 0) {
    int run = 0;
#pragma unroll
    for (int i = 0; i < 4; i++) { int c = wsum[i]; wsum[i] = run; run += c; }
  }
  __syncthreads();
  int incl = inc + wsum[wid];
  lcur[t] = base + incl - v;  // exclusive start
  int node = b * 256 + t;
  if (node < N_NODES) offs[node] = base + incl;  // end position
  __syncthreads();
  for (int i = t; i < cnt; i += 256) {
    unsigned int pv = binned[base + i];
    int pos = atomicAdd(&lcur[pv >> 17], 1);
    csr[pos] = (int)(pv & 0x1FFFFu);
  }
}

// ==================== fp16 conversion ====================

__global__ __launch_bounds__(256) void to_half2(const float* __restrict__ in,
                                                __half2* __restrict__ out, int n2) {
  int i = blockIdx.x * 256 + threadIdx.x;
  if (i >= n2) return;
  float2 v = reinterpret_cast<const float2*>(in)[i];
  out[i] = __floats2half2_rn(v.x, v.y);
}

// ==================== fused layers (R5 structure: high-occupancy gathers) ====

// Layer 1: wave per node. x fp16 (16 half2/row). Quarter-wave (16 lanes) per
// row, 4 edges/stride, unroll 4 -> 16 rows in flight per wave.
__global__ __launch_bounds__(256) void layer1_fused(
    const __half2* __restrict__ xh, const int* __restrict__ csr,
    const int* __restrict__ offs, const float* __restrict__ Wl,
    const float* __restrict__ Wr, const float* __restrict__ b,
    const float* __restrict__ g, const float* __restrict__ be,
    __half* __restrict__ h1) {
  int node = blockIdx.x * 4 + (threadIdx.x >> 6);
  if (node >= N_NODES) return;
  int lane = threadIdx.x & 63;
  int c = lane & 15, slot4 = lane >> 4;

  int end = offs[node];
  int start = node ? offs[node - 1] : 0;
  float inv = 1.0f / fmaxf((float)(end - start), 1.0f);

  float ax = 0.0f, ay = 0.0f;
  int slot = start + slot4;
  for (; slot + 12 < end; slot += 16) {
    int s0 = csr[slot], s1 = csr[slot + 4], s2 = csr[slot + 8], s3 = csr[slot + 12];
    float2 f0 = __half22float2(xh[(size_t)s0 * 16 + c]);
    float2 f1 = __half22float2(xh[(size_t)s1 * 16 + c]);
    float2 f2 = __half22float2(xh[(size_t)s2 * 16 + c]);
    float2 f3 = __half22float2(xh[(size_t)s3 * 16 + c]);
    ax += (f0.x + f1.x) + (f2.x + f3.x);
    ay += (f0.y + f1.y) + (f2.y + f3.y);
  }
  for (; slot < end; slot += 4) {
    float2 f = __half22float2(xh[(size_t)csr[slot] * 16 + c]);
    ax += f.x;
    ay += f.y;
  }
  ax += __shfl_xor(ax, 16); ay += __shfl_xor(ay, 16);
  ax += __shfl_xor(ax, 32); ay += __shfl_xor(ay, 32);

  float2 xs = __half22float2(xh[(size_t)node * 16 + c]);

  int o = lane;
  float accO = b[o];
#pragma unroll
  for (int k = 0; k < 32; k++) {
    float ak = __shfl((k & 1) ? ay : ax, k >> 1);
    float xk = __shfl((k & 1) ? xs.y : xs.x, k >> 1);
    accO = fmaf(ak * inv, Wl[k * 64 + o], accO);
    accO = fmaf(xk, Wr[k * 64 + o], accO);
  }

  // LayerNorm over 64 lanes + ReLU
  float s = accO;
#pragma unroll
  for (int off = 32; off; off >>= 1) s += __shfl_xor(s, off);
  float mu = s * (1.0f / 64.0f);
  float d = accO - mu;
  float v2 = d * d;
#pragma unroll
  for (int off = 32; off; off >>= 1) v2 += __shfl_xor(v2, off);
  float o2 = d * rsqrtf(v2 * (1.0f / 64.0f) + 1e-5f) * g[o] + be[o];
  h1[(size_t)node * 64 + o] = __float2half(fmaxf(o2, 0.0f));
}

// Layer 2 (+ fused layer-3 node part): wave per node. h1 fp16 (32 half2/row).
// Half-wave (32 lanes) per row, 2 edges/stride, unroll 4 -> 8 rows in flight.
// Epilogue keeps h2 in registers: y3 = h2 @ W_l3, out_self = h2 @ W_r3 + b3.
__global__ __launch_bounds__(256) void layer2_fused(
    const __half2* __restrict__ h1q, const int* __restrict__ csr,
    const int* __restrict__ offs, const float* __restrict__ Wl,
    const float* __restrict__ Wr, const float* __restrict__ b,
    const float* __restrict__ g, const float* __restrict__ be,
    const float* __restrict__ Wl3, const float* __restrict__ Wr3,
    const float* __restrict__ b3, float* __restrict__ y3,
    float* __restrict__ out) {
  int node = blockIdx.x * 4 + (threadIdx.x >> 6);
  if (node >= N_NODES) return;
  int lane = threadIdx.x & 63;
  int c = lane & 31, half = lane >> 5;

  int end = offs[node];
  int start = node ? offs[node - 1] : 0;
  float inv = 1.0f / fmaxf((float)(end - start), 1.0f);

  float ax = 0.0f, ay = 0.0f;
  int slot = start + half;
  for (; slot + 6 < end; slot += 8) {
    int s0 = csr[slot], s1 = csr[slot + 2], s2 = csr[slot + 4], s3 = csr[slot + 6];
    float2 f0 = __half22float2(h1q[(size_t)s0 * 32 + c]);
    float2 f1 = __half22float2(h1q[(size_t)s1 * 32 + c]);
    float2 f2 = __half22float2(h1q[(size_t)s2 * 32 + c]);
    float2 f3 = __half22float2(h1q[(size_t)s3 * 32 + c]);
    ax += (f0.x + f1.x) + (f2.x + f3.x);
    ay += (f0.y + f1.y) + (f2.y + f3.y);
  }
  for (; slot < end; slot += 2) {
    float2 f = __half22float2(h1q[(size_t)csr[slot] * 32 + c]);
    ax += f.x;
    ay += f.y;
  }
  ax += __shfl_xor(ax, 32);
  ay += __shfl_xor(ay, 32);

  float2 hs = __half22float2(h1q[(size_t)node * 32 + c]);

  int o = lane;
  float accO = b[o];
#pragma unroll
  for (int k = 0; k < 64; k++) {
    float ak = __shfl((k & 1) ? ay : ax, k >> 1);
    float hk = __shfl((k & 1) ? hs.y : hs.x, k >> 1);
    accO = fmaf(ak * inv, Wl[k * 64 + o], accO);
    accO = fmaf(hk, Wr[k * 64 + o], accO);
  }

  float s = accO;
#pragma unroll
  for (int off = 32; off; off >>= 1) s += __shfl_xor(s, off);
  float mu = s * (1.0f / 64.0f);
  float d = accO - mu;
  float v2 = d * d;
#pragma unroll
  for (int off = 32; off; off >>= 1) v2 += __shfl_xor(v2, off);
  float h2v = fmaxf(d * rsqrtf(v2 * (1.0f / 64.0f) + 1e-5f) * g[o] + be[o], 0.0f);

  // fused layer-3 node part: lane o holds h2[o]
  float t0 = h2v * Wl3[o * 2 + 0];
  float t1 = h2v * Wl3[o * 2 + 1];
  float t2 = h2v * Wr3[o * 2 + 0];
  float t3 = h2v * Wr3[o * 2 + 1];
#pragma unroll
  for (int off = 32; off; off >>= 1) {
    t0 += __shfl_xor(t0, off);
    t1 += __shfl_xor(t1, off);
    t2 += __shfl_xor(t2, off);
    t3 += __shfl_xor(t3, off);
  }
  if (lane == 0) {
    reinterpret_cast<float2*>(y3)[node] = make_float2(t0, t1);
    reinterpret_cast<float2*>(out)[node] = make_float2(t2 + b3[0], t3 + b3[1]);
  }
}

// Layer 3 gather: wave per node, edges strided across lanes, shfl reduce.
// y3 is 800KB -> cache-resident.
__global__ __launch_bounds__(256) void gather3(
    const float* __restrict__ y, const int* __restrict__ csr,
    const int* __restrict__ offs, float* __restrict__ out) {
  int node = blockIdx.x * 4 + (threadIdx.x >> 6);
  if (node >= N_NODES) return;
  int lane = threadIdx.x & 63;

  int end = offs[node];
  int start = node ? offs[node - 1] : 0;
  float inv = 1.0f / fmaxf((float)(end - start), 1.0f);

  float s0 = 0.f, s1 = 0.f;
  for (int slot = start + lane; slot < end; slot += 64) {
    float2 v = reinterpret_cast<const float2*>(y)[csr[slot]];
    s0 += v.x;
    s1 += v.y;
  }
#pragma unroll
  for (int off = 32; off; off >>= 1) {
    s0 += __shfl_xor(s0, off);
    s1 += __shfl_xor(s1, off);
  }
  if (lane == 0) {
    out[(size_t)node * 2 + 0] += s0 * inv;
    out[(size_t)node * 2 + 1] += s1 * inv;
  }
}

// ==================== launch ====================

extern "C" void kernel_launch(void* const* d_in, const int* in_sizes, int n_in,
                              void* d_out, int out_size, void* d_ws, size_t ws_size,
                              hipStream_t stream) {
  const float* x = (const float*)d_in[0];
  const int* ei = (const int*)d_in[1];
  const int* src = ei;
  const int* tgt = ei + N_EDGES;
  const float* Wl1 = (const float*)d_in[2];
  const float* Wr1 = (const float*)d_in[3];
  const float* b1 = (const float*)d_in[4];
  const float* g1 = (const float*)d_in[5];
  const float* be1 = (const float*)d_in[6];
  const float* Wl2 = (const float*)d_in[7];
  const float* Wr2 = (const float*)d_in[8];
  const float* b2 = (const float*)d_in[9];
  const float* g2 = (const float*)d_in[10];
  const float* be2 = (const float*)d_in[11];
  const float* Wl3 = (const float*)d_in[12];
  const float* Wr3 = (const float*)d_in[13];
  const float* b3 = (const float*)d_in[14];
  float* out = (float*)d_out;
  char* ws = (char*)d_ws;

  // ---- workspace layout (~34 MB) ----
  size_t p = 0;
  auto carve = [&](size_t bytes) {
    size_t r = p;
    p += (bytes + 255) & ~(size_t)255;
    return r;
  };
  size_t count_off = carve((size_t)NBK * 4);
  size_t base_off = carve((size_t)(NBK + 1) * 4);
  size_t cursor_off = carve((size_t)NBK * 4);
  size_t bh_off = carve((size_t)NBLK_BIN * NBK * 4);  // block histograms (611KB)
  size_t offs_off = carve((size_t)N_NODES * 4);
  size_t csr_off = carve((size_t)N_EDGES * 4);
  size_t xh_off = carve((size_t)N_NODES * 32 * 2);  // x fp16; later y3 (800KB)
  size_t h1_off = carve((size_t)N_NODES * 64 * 2);  // h1 fp16; binned aliases (12.8MB)

  int* count = (int*)(ws + count_off);
  int* bktBase = (int*)(ws + base_off);
  int* cursor = (int*)(ws + cursor_off);
  int* blockHist = (int*)(ws + bh_off);
  int* offs = (int*)(ws + offs_off);
  int* csr = (int*)(ws + csr_off);
  __half2* xh = (__half2*)(ws + xh_off);
  __half* h1 = (__half*)(ws + h1_off);
  unsigned int* binned = (unsigned int*)h1;  // dead before h1 is written

  hipMemsetAsync(count, 0, (size_t)NBK * 4, stream);
  bin_hist<<<NBLK_BIN, 256, 0, stream>>>(tgt, count, blockHist);
  bin_scan<<<1, 512, 0, stream>>>(count, bktBase, cursor);
  bin_scatter<<<NBLK_BIN, 256, 0, stream>>>(src, tgt, blockHist, cursor, binned);
  bucket_sort<<<NBK, 256, 0, stream>>>(binned, bktBase, csr, offs);

  to_half2<<<(N_NODES * 16 + 255) / 256, 256, 0, stream>>>(x, xh, N_NODES * 16);

  layer1_fused<<<(N_NODES + 3) / 4, 256, 0, stream>>>(
      xh, csr, offs, Wl1, Wr1, b1, g1, be1, h1);

  float* y3 = (float*)xh;  // xh dead after layer1; reuse (800KB)
  layer2_fused<<<(N_NODES + 3) / 4, 256, 0, stream>>>(
      (const __half2*)h1, csr, offs, Wl2, Wr2, b2, g2, be2, Wl3, Wr3, b3, y3, out);

  gather3<<<(N_NODES + 3) / 4, 256, 0, stream>>>(y3, csr, offs, out);
}

// Round 10
// 341.449 us; speedup vs baseline: 1.7764x; 1.1429x over previous
//
#include <hip/hip_runtime.h>
#include <hip/hip_fp16.h>

#define N_NODES 100000
#define N_EDGES 3200000
#define NBK 391          // ceil(N_NODES / 256) buckets, 256 nodes each
#define EPB 8192         // edges per block in binning passes
#define NBLK_BIN 391     // ceil(N_EDGES / EPB)

// ==================== common helpers ====================

__device__ __forceinline__ int wave_incl_scan_i(int v) {
  int lane = threadIdx.x & 63;
#pragma unroll
  for (int off = 1; off < 64; off <<= 1) {
    int n = __shfl_up(v, off);
    if (lane >= off) v += n;
  }
  return v;
}

// exact f32 broadcast from lane l (uniform l) via v_readlane: no DS-pipe use
__device__ __forceinline__ float bcastf(float v, int l) {
  return __int_as_float(__builtin_amdgcn_readlane(__float_as_int(v), l));
}

// ==================== CSR build: bucketed counting sort ====================

// Pass A: per-bucket edge counts; also saves this block's histogram for reuse.
__global__ __launch_bounds__(256) void bin_hist(const int* __restrict__ tgt,
                                                int* __restrict__ count,
                                                int* __restrict__ blockHist) {
  __shared__ int hist[NBK];
  int t = threadIdx.x;
  for (int i = t; i < NBK; i += 256) hist[i] = 0;
  __syncthreads();
  int e0 = blockIdx.x * EPB;
  int e1 = min(e0 + EPB, N_EDGES);
  for (int e = e0 + t; e < e1; e += 256) atomicAdd(&hist[tgt[e] >> 8], 1);
  __syncthreads();
  int* bh = blockHist + (size_t)blockIdx.x * NBK;
  for (int i = t; i < NBK; i += 256) {
    int c = hist[i];
    bh[i] = c;
    if (c) atomicAdd(&count[i], c);
  }
}

__global__ __launch_bounds__(512) void bin_scan(const int* __restrict__ count,
                                                int* __restrict__ bktBase,
                                                int* __restrict__ cursor) {
  __shared__ int lds[8];
  int t = threadIdx.x;
  int v = (t < NBK) ? count[t] : 0;
  int inc = wave_incl_scan_i(v);
  int lane = t & 63, wid = t >> 6;
  if (lane == 63) lds[wid] = inc;
  __syncthreads();
  if (t == 0) {
    int run = 0;
#pragma unroll
    for (int i = 0; i < 8; i++) { int c = lds[i]; lds[i] = run; run += c; }
  }
  __syncthreads();
  int ex = inc - v + lds[wid];
  if (t < NBK) { bktBase[t] = ex; cursor[t] = ex; }
  if (t == NBK) bktBase[NBK] = ex;  // == N_EDGES
}

// Pass B: scatter packed (src | tgtLocal<<17), reusing the saved histograms.
__global__ __launch_bounds__(256) void bin_scatter(const int* __restrict__ src,
                                                   const int* __restrict__ tgt,
                                                   const int* __restrict__ blockHist,
                                                   int* __restrict__ cursor,
                                                   unsigned int* __restrict__ binned) {
  __shared__ int hist[NBK];
  __shared__ int lbase[NBK];
  int t = threadIdx.x;
  const int* bh = blockHist + (size_t)blockIdx.x * NBK;
  for (int i = t; i < NBK; i += 256) {
    int c = bh[i];
    lbase[i] = c ? atomicAdd(&cursor[i], c) : 0;
    hist[i] = 0;  // local cursor
  }
  __syncthreads();
  int e0 = blockIdx.x * EPB;
  int e1 = min(e0 + EPB, N_EDGES);
  for (int e = e0 + t; e < e1; e += 256) {
    int tg = tgt[e];
    int bkt = tg >> 8;
    int lo = atomicAdd(&hist[bkt], 1);
    binned[lbase[bkt] + lo] = (unsigned int)src[e] | ((unsigned int)(tg & 255) << 17);
  }
}

__global__ __launch_bounds__(256) void bucket_sort(const unsigned int* __restrict__ binned,
                                                   const int* __restrict__ bktBase,
                                                   int* __restrict__ csr,
                                                   int* __restrict__ offs) {
  __shared__ int deg[256];
  __shared__ int lcur[256];
  __shared__ int wsum[4];
  int b = blockIdx.x;
  int t = threadIdx.x;
  int base = bktBase[b];
  int cnt = bktBase[b + 1] - base;
  deg[t] = 0;
  __syncthreads();
  for (int i = t; i < cnt; i += 256) atomicAdd(&deg[binned[base + i] >> 17], 1);
  __syncthreads();
  int v = deg[t];
  int inc = wave_incl_scan_i(v);
  int lane = t & 63, wid = t >> 6;
  if (lane == 63) wsum[wid] = inc;
  __syncthreads();
  if (t == 0) {
    int run = 0;
#pragma unroll
    for (int i = 0; i < 4; i++) { int c = wsum[i]; wsum[i] = run; run += c; }
  }
  __syncthreads();
  int incl = inc + wsum[wid];
  lcur[t] = base + incl - v;  // exclusive start
  int node = b * 256 + t;
  if (node < N_NODES) offs[node] = base + incl;  // end position
  __syncthreads();
  for (int i = t; i < cnt; i += 256) {
    unsigned int pv = binned[base + i];
    int pos = atomicAdd(&lcur[pv >> 17], 1);
    csr[pos] = (int)(pv & 0x1FFFFu);
  }
}

// ==================== fp16 conversion ====================

__global__ __launch_bounds__(256) void to_half2(const float* __restrict__ in,
                                                __half2* __restrict__ out, int n2) {
  int i = blockIdx.x * 256 + threadIdx.x;
  if (i >= n2) return;
  float2 v = reinterpret_cast<const float2*>(in)[i];
  out[i] = __floats2half2_rn(v.x, v.y);
}

// ==================== fused layers ====================

// Layer 1: wave per node. x fp16 (16 half2/row). Quarter-wave (16 lanes) per
// row, 4 edges/stride, unroll 4 -> 16 rows in flight; parallel predicated tail.
__global__ __launch_bounds__(256) void layer1_fused(
    const __half2* __restrict__ xh, const int* __restrict__ csr,
    const int* __restrict__ offs, const float* __restrict__ Wl,
    const float* __restrict__ Wr, const float* __restrict__ b,
    const float* __restrict__ g, const float* __restrict__ be,
    __half* __restrict__ h1) {
  int node = blockIdx.x * 4 + (threadIdx.x >> 6);
  if (node >= N_NODES) return;
  int lane = threadIdx.x & 63;
  int c = lane & 15, slot4 = lane >> 4;

  int end = offs[node];
  int start = node ? offs[node - 1] : 0;
  float inv = 1.0f / fmaxf((float)(end - start), 1.0f);

  float ax = 0.0f, ay = 0.0f;
  int slot = start + slot4;
  for (; slot + 12 < end; slot += 16) {
    int s0 = csr[slot], s1 = csr[slot + 4], s2 = csr[slot + 8], s3 = csr[slot + 12];
    float2 f0 = __half22float2(xh[(size_t)s0 * 16 + c]);
    float2 f1 = __half22float2(xh[(size_t)s1 * 16 + c]);
    float2 f2 = __half22float2(xh[(size_t)s2 * 16 + c]);
    float2 f3 = __half22float2(xh[(size_t)s3 * 16 + c]);
    ax += (f0.x + f1.x) + (f2.x + f3.x);
    ay += (f0.y + f1.y) + (f2.y + f3.y);
  }
  if (slot < end) {  // parallel predicated tail (up to 3 rows, issued at once)
    int i1 = slot + 4, i2 = slot + 8;
    int s0 = csr[slot];
    int s1 = (i1 < end) ? csr[i1] : s0;
    int s2 = (i2 < end) ? csr[i2] : s0;
    float m1 = (i1 < end) ? 1.0f : 0.0f;
    float m2 = (i2 < end) ? 1.0f : 0.0f;
    float2 f0 = __half22float2(xh[(size_t)s0 * 16 + c]);
    float2 f1 = __half22float2(xh[(size_t)s1 * 16 + c]);
    float2 f2 = __half22float2(xh[(size_t)s2 * 16 + c]);
    ax += f0.x + m1 * f1.x + m2 * f2.x;
    ay += f0.y + m1 * f1.y + m2 * f2.y;
  }
  ax += __shfl_xor(ax, 16); ay += __shfl_xor(ay, 16);
  ax += __shfl_xor(ax, 32); ay += __shfl_xor(ay, 32);

  float2 xs = __half22float2(xh[(size_t)node * 16 + c]);

  int o = lane;
  float accO = b[o];
#pragma unroll
  for (int k = 0; k < 32; k++) {
    float ak = bcastf((k & 1) ? ay : ax, k >> 1);
    float xk = bcastf((k & 1) ? xs.y : xs.x, k >> 1);
    accO = fmaf(ak * inv, Wl[k * 64 + o], accO);
    accO = fmaf(xk, Wr[k * 64 + o], accO);
  }

  // LayerNorm over 64 lanes + ReLU
  float s = accO;
#pragma unroll
  for (int off = 32; off; off >>= 1) s += __shfl_xor(s, off);
  float mu = s * (1.0f / 64.0f);
  float d = accO - mu;
  float v2 = d * d;
#pragma unroll
  for (int off = 32; off; off >>= 1) v2 += __shfl_xor(v2, off);
  float o2 = d * rsqrtf(v2 * (1.0f / 64.0f) + 1e-5f) * g[o] + be[o];
  h1[(size_t)node * 64 + o] = __float2half(fmaxf(o2, 0.0f));
}

// Layer 2 (+ fused layer-3 node part): wave per node. h1 fp16 (32 half2/row).
// Half-wave per row, 2 edges/stride, unroll 4 -> 8 rows in flight; parallel
// predicated tail. Epilogue keeps h2 in regs: y3 = h2@W_l3, out = h2@W_r3+b3.
__global__ __launch_bounds__(256) void layer2_fused(
    const __half2* __restrict__ h1q, const int* __restrict__ csr,
    const int* __restrict__ offs, const float* __restrict__ Wl,
    const float* __restrict__ Wr, const float* __restrict__ b,
    const float* __restrict__ g, const float* __restrict__ be,
    const float* __restrict__ Wl3, const float* __restrict__ Wr3,
    const float* __restrict__ b3, float* __restrict__ y3,
    float* __restrict__ out) {
  int node = blockIdx.x * 4 + (threadIdx.x >> 6);
  if (node >= N_NODES) return;
  int lane = threadIdx.x & 63;
  int c = lane & 31, half = lane >> 5;

  int end = offs[node];
  int start = node ? offs[node - 1] : 0;
  float inv = 1.0f / fmaxf((float)(end - start), 1.0f);

  float ax = 0.0f, ay = 0.0f;
  int slot = start + half;
  for (; slot + 6 < end; slot += 8) {
    int s0 = csr[slot], s1 = csr[slot + 2], s2 = csr[slot + 4], s3 = csr[slot + 6];
    float2 f0 = __half22float2(h1q[(size_t)s0 * 32 + c]);
    float2 f1 = __half22float2(h1q[(size_t)s1 * 32 + c]);
    float2 f2 = __half22float2(h1q[(size_t)s2 * 32 + c]);
    float2 f3 = __half22float2(h1q[(size_t)s3 * 32 + c]);
    ax += (f0.x + f1.x) + (f2.x + f3.x);
    ay += (f0.y + f1.y) + (f2.y + f3.y);
  }
  if (slot < end) {  // parallel predicated tail (up to 3 rows, issued at once)
    int i1 = slot + 2, i2 = slot + 4;
    int s0 = csr[slot];
    int s1 = (i1 < end) ? csr[i1] : s0;
    int s2 = (i2 < end) ? csr[i2] : s0;
    float m1 = (i1 < end) ? 1.0f : 0.0f;
    float m2 = (i2 < end) ? 1.0f : 0.0f;
    float2 f0 = __half22float2(h1q[(size_t)s0 * 32 + c]);
    float2 f1 = __half22float2(h1q[(size_t)s1 * 32 + c]);
    float2 f2 = __half22float2(h1q[(size_t)s2 * 32 + c]);
    ax += f0.x + m1 * f1.x + m2 * f2.x;
    ay += f0.y + m1 * f1.y + m2 * f2.y;
  }
  ax += __shfl_xor(ax, 32);
  ay += __shfl_xor(ay, 32);

  float2 hs = __half22float2(h1q[(size_t)node * 32 + c]);

  int o = lane;
  float accO = b[o];
#pragma unroll
  for (int k = 0; k < 64; k++) {
    float ak = bcastf((k & 1) ? ay : ax, k >> 1);
    float hk = bcastf((k & 1) ? hs.y : hs.x, k >> 1);
    accO = fmaf(ak * inv, Wl[k * 64 + o], accO);
    accO = fmaf(hk, Wr[k * 64 + o], accO);
  }

  float s = accO;
#pragma unroll
  for (int off = 32; off; off >>= 1) s += __shfl_xor(s, off);
  float mu = s * (1.0f / 64.0f);
  float d = accO - mu;
  float v2 = d * d;
#pragma unroll
  for (int off = 32; off; off >>= 1) v2 += __shfl_xor(v2, off);
  float h2v = fmaxf(d * rsqrtf(v2 * (1.0f / 64.0f) + 1e-5f) * g[o] + be[o], 0.0f);

  // fused layer-3 node part: lane o holds h2[o]
  float t0 = h2v * Wl3[o * 2 + 0];
  float t1 = h2v * Wl3[o * 2 + 1];
  float t2 = h2v * Wr3[o * 2 + 0];
  float t3 = h2v * Wr3[o * 2 + 1];
#pragma unroll
  for (int off = 32; off; off >>= 1) {
    t0 += __shfl_xor(t0, off);
    t1 += __shfl_xor(t1, off);
    t2 += __shfl_xor(t2, off);
    t3 += __shfl_xor(t3, off);
  }
  if (lane == 0) {
    reinterpret_cast<float2*>(y3)[node] = make_float2(t0, t1);
    reinterpret_cast<float2*>(out)[node] = make_float2(t2 + b3[0], t3 + b3[1]);
  }
}

// Layer 3 gather: wave per node, edges strided across lanes, shfl reduce.
// y3 is 800KB -> cache-resident.
__global__ __launch_bounds__(256) void gather3(
    const float* __restrict__ y, const int* __restrict__ csr,
    const int* __restrict__ offs, float* __restrict__ out) {
  int node = blockIdx.x * 4 + (threadIdx.x >> 6);
  if (node >= N_NODES) return;
  int lane = threadIdx.x & 63;

  int end = offs[node];
  int start = node ? offs[node - 1] : 0;
  float inv = 1.0f / fmaxf((float)(end - start), 1.0f);

  float s0 = 0.f, s1 = 0.f;
  for (int slot = start + lane; slot < end; slot += 64) {
    float2 v = reinterpret_cast<const float2*>(y)[csr[slot]];
    s0 += v.x;
    s1 += v.y;
  }
#pragma unroll
  for (int off = 32; off; off >>= 1) {
    s0 += __shfl_xor(s0, off);
    s1 += __shfl_xor(s1, off);
  }
  if (lane == 0) {
    out[(size_t)node * 2 + 0] += s0 * inv;
    out[(size_t)node * 2 + 1] += s1 * inv;
  }
}

// ==================== launch ====================

extern "C" void kernel_launch(void* const* d_in, const int* in_sizes, int n_in,
                              void* d_out, int out_size, void* d_ws, size_t ws_size,
                              hipStream_t stream) {
  const float* x = (const float*)d_in[0];
  const int* ei = (const int*)d_in[1];
  const int* src = ei;
  const int* tgt = ei + N_EDGES;
  const float* Wl1 = (const float*)d_in[2];
  const float* Wr1 = (const float*)d_in[3];
  const float* b1 = (const float*)d_in[4];
  const float* g1 = (const float*)d_in[5];
  const float* be1 = (const float*)d_in[6];
  const float* Wl2 = (const float*)d_in[7];
  const float* Wr2 = (const float*)d_in[8];
  const float* b2 = (const float*)d_in[9];
  const float* g2 = (const float*)d_in[10];
  const float* be2 = (const float*)d_in[11];
  const float* Wl3 = (const float*)d_in[12];
  const float* Wr3 = (const float*)d_in[13];
  const float* b3 = (const float*)d_in[14];
  float* out = (float*)d_out;
  char* ws = (char*)d_ws;

  // ---- workspace layout (~34 MB) ----
  size_t p = 0;
  auto carve = [&](size_t bytes) {
    size_t r = p;
    p += (bytes + 255) & ~(size_t)255;
    return r;
  };
  size_t count_off = carve((size_t)NBK * 4);
  size_t base_off = carve((size_t)(NBK + 1) * 4);
  size_t cursor_off = carve((size_t)NBK * 4);
  size_t bh_off = carve((size_t)NBLK_BIN * NBK * 4);  // block histograms (611KB)
  size_t offs_off = carve((size_t)N_NODES * 4);
  size_t csr_off = carve((size_t)N_EDGES * 4);
  size_t xh_off = carve((size_t)N_NODES * 32 * 2);  // x fp16; later y3 (800KB)
  size_t h1_off = carve((size_t)N_NODES * 64 * 2);  // h1 fp16; binned aliases (12.8MB)

  int* count = (int*)(ws + count_off);
  int* bktBase = (int*)(ws + base_off);
  int* cursor = (int*)(ws + cursor_off);
  int* blockHist = (int*)(ws + bh_off);
  int* offs = (int*)(ws + offs_off);
  int* csr = (int*)(ws + csr_off);
  __half2* xh = (__half2*)(ws + xh_off);
  __half* h1 = (__half*)(ws + h1_off);
  unsigned int* binned = (unsigned int*)h1;  // dead before h1 is written

  hipMemsetAsync(count, 0, (size_t)NBK * 4, stream);
  bin_hist<<<NBLK_BIN, 256, 0, stream>>>(tgt, count, blockHist);
  bin_scan<<<1, 512, 0, stream>>>(count, bktBase, cursor);
  bin_scatter<<<NBLK_BIN, 256, 0, stream>>>(src, tgt, blockHist, cursor, binned);
  bucket_sort<<<NBK, 256, 0, stream>>>(binned, bktBase, csr, offs);

  to_half2<<<(N_NODES * 16 + 255) / 256, 256, 0, stream>>>(x, xh, N_NODES * 16);

  layer1_fused<<<(N_NODES + 3) / 4, 256, 0, stream>>>(
      xh, csr, offs, Wl1, Wr1, b1, g1, be1, h1);

  float* y3 = (float*)xh;  // xh dead after layer1; reuse (800KB)
  layer2_fused<<<(N_NODES + 3) / 4, 256, 0, stream>>>(
      (const __half2*)h1, csr, offs, Wl2, Wr2, b2, g2, be2, Wl3, Wr3, b3, y3, out);

  gather3<<<(N_NODES + 3) / 4, 256, 0, stream>>>(y3, csr, offs, out);
}

// Round 11
// 327.788 us; speedup vs baseline: 1.8504x; 1.0417x over previous
//
#include <hip/hip_runtime.h>
#include <hip/hip_fp16.h>

#define N_NODES 100000
#define N_EDGES 3200000
#define NBK 391          // ceil(N_NODES / 256) buckets, 256 nodes each
#define CAP 9216         // fixed per-bucket csr capacity (mean 8192, +11 sigma)
#define EPB 8192         // edges per block in binning passes
#define NBLK_BIN 391     // ceil(N_EDGES / EPB)

// ==================== common helpers ====================

__device__ __forceinline__ int wave_incl_scan_i(int v) {
  int lane = threadIdx.x & 63;
#pragma unroll
  for (int off = 1; off < 64; off <<= 1) {
    int n = __shfl_up(v, off);
    if (lane >= off) v += n;
  }
  return v;
}

// exact f32 broadcast from lane l (uniform l) via v_readlane: no DS-pipe use
__device__ __forceinline__ float bcastf(float v, int l) {
  return __int_as_float(__builtin_amdgcn_readlane(__float_as_int(v), l));
}

__device__ __forceinline__ __half2 h2zero() { return __float2half2_rn(0.0f); }

// packed cross-lane reduce: shfl the half2 as int, add packed
__device__ __forceinline__ __half2 h2shfl_xor_add(__half2 a, int off) {
  int ai = *reinterpret_cast<int*>(&a);
  int bi = __shfl_xor(ai, off);
  return __hadd2(a, *reinterpret_cast<__half2*>(&bi));
}

// ==================== CSR build: fixed-capacity bucketed sort ====================

__global__ __launch_bounds__(256) void init_cursor(int* __restrict__ cursor) {
  int i = blockIdx.x * 256 + threadIdx.x;
  if (i < NBK) cursor[i] = i * CAP;
}

// Count per-bucket in LDS, reserve contiguous runs from cursor, scatter packed
// (src | tgtLocal<<17) into the bucket's fixed region.
__global__ __launch_bounds__(256) void bin_scatter(const int* __restrict__ src,
                                                   const int* __restrict__ tgt,
                                                   int* __restrict__ cursor,
                                                   unsigned int* __restrict__ binned) {
  __shared__ int hist[NBK];
  __shared__ int lbase[NBK];
  int t = threadIdx.x;
  for (int i = t; i < NBK; i += 256) hist[i] = 0;
  __syncthreads();
  int e0 = blockIdx.x * EPB;
  int e1 = min(e0 + EPB, N_EDGES);
  for (int e = e0 + t; e < e1; e += 256) atomicAdd(&hist[tgt[e] >> 8], 1);
  __syncthreads();
  for (int i = t; i < NBK; i += 256) {
    int c = hist[i];
    lbase[i] = c ? atomicAdd(&cursor[i], c) : 0;
    hist[i] = 0;  // reuse as local cursor
  }
  __syncthreads();
  for (int e = e0 + t; e < e1; e += 256) {
    int tg = tgt[e];
    int bkt = tg >> 8;
    int lo = atomicAdd(&hist[bkt], 1);
    binned[lbase[bkt] + lo] = (unsigned int)src[e] | ((unsigned int)(tg & 255) << 17);
  }
}

// One block per bucket: degree count + scan -> offs (end positions), place
// src ids into csr (bucket-padded; start of first node in bucket = b*CAP).
__global__ __launch_bounds__(256) void bucket_sort(const unsigned int* __restrict__ binned,
                                                   const int* __restrict__ cursor,
                                                   int* __restrict__ csr,
                                                   int* __restrict__ offs) {
  __shared__ int deg[256];
  __shared__ int lcur[256];
  __shared__ int wsum[4];
  int b = blockIdx.x;
  int t = threadIdx.x;
  int base = b * CAP;
  int cnt = cursor[b] - base;
  deg[t] = 0;
  __syncthreads();
  for (int i = t; i < cnt; i += 256) atomicAdd(&deg[binned[base + i] >> 17], 1);
  __syncthreads();
  int v = deg[t];
  int inc = wave_incl_scan_i(v);
  int lane = t & 63, wid = t >> 6;
  if (lane == 63) wsum[wid] = inc;
  __syncthreads();
  if (t == 0) {
    int run = 0;
#pragma unroll
    for (int i = 0; i < 4; i++) { int c = wsum[i]; wsum[i] = run; run += c; }
  }
  __syncthreads();
  int incl = inc + wsum[wid];
  lcur[t] = base + incl - v;  // exclusive start
  int node = b * 256 + t;
  if (node < N_NODES) offs[node] = base + incl;  // end position
  __syncthreads();
  for (int i = t; i < cnt; i += 256) {
    unsigned int pv = binned[base + i];
    int pos = atomicAdd(&lcur[pv >> 17], 1);
    csr[pos] = (int)(pv & 0x1FFFFu);
  }
}

// ==================== fp16 conversion ====================

__global__ __launch_bounds__(256) void to_half2(const float* __restrict__ in,
                                                __half2* __restrict__ out, int n2) {
  int i = blockIdx.x * 256 + threadIdx.x;
  if (i >= n2) return;
  float2 v = reinterpret_cast<const float2*>(in)[i];
  out[i] = __floats2half2_rn(v.x, v.y);
}

// ==================== fused layers (packed-fp16 gather accumulate) ====================

// Layer 1: wave per node. x fp16 (16 half2/row). Quarter-wave per row,
// 4 edges/stride, unroll 4 -> 16 rows in flight; packed __hadd2 accumulate.
__global__ __launch_bounds__(256) void layer1_fused(
    const __half2* __restrict__ xh, const int* __restrict__ csr,
    const int* __restrict__ offs, const float* __restrict__ Wl,
    const float* __restrict__ Wr, const float* __restrict__ b,
    const float* __restrict__ g, const float* __restrict__ be,
    __half* __restrict__ h1) {
  int node = blockIdx.x * 4 + (threadIdx.x >> 6);
  if (node >= N_NODES) return;
  int lane = threadIdx.x & 63;
  int c = lane & 15, slot4 = lane >> 4;

  int end = offs[node];
  int start = (node & 255) ? offs[node - 1] : (node >> 8) * CAP;
  float inv = 1.0f / fmaxf((float)(end - start), 1.0f);

  __half2 A0 = h2zero(), A1 = h2zero(), A2 = h2zero(), A3 = h2zero();
  int slot = start + slot4;
  for (; slot + 12 < end; slot += 16) {
    int s0 = csr[slot], s1 = csr[slot + 4], s2 = csr[slot + 8], s3 = csr[slot + 12];
    A0 = __hadd2(A0, xh[(size_t)s0 * 16 + c]);
    A1 = __hadd2(A1, xh[(size_t)s1 * 16 + c]);
    A2 = __hadd2(A2, xh[(size_t)s2 * 16 + c]);
    A3 = __hadd2(A3, xh[(size_t)s3 * 16 + c]);
  }
  if (slot < end) {  // predicated parallel tail (up to 3 rows)
    int i1 = slot + 4, i2 = slot + 8;
    int s0 = csr[slot];
    int s1 = (i1 < end) ? csr[i1] : s0;
    int s2 = (i2 < end) ? csr[i2] : s0;
    __half2 u0 = xh[(size_t)s0 * 16 + c];
    __half2 u1 = xh[(size_t)s1 * 16 + c];
    __half2 u2 = xh[(size_t)s2 * 16 + c];
    A0 = __hadd2(A0, u0);
    A1 = __hadd2(A1, (i1 < end) ? u1 : h2zero());
    A2 = __hadd2(A2, (i2 < end) ? u2 : h2zero());
  }
  __half2 Ah = __hadd2(__hadd2(A0, A1), __hadd2(A2, A3));
  Ah = h2shfl_xor_add(Ah, 16);
  Ah = h2shfl_xor_add(Ah, 32);
  float2 fa = __half22float2(Ah);
  float ax = fa.x * inv, ay = fa.y * inv;

  float2 xs = __half22float2(xh[(size_t)node * 16 + c]);

  int o = lane;
  float accO = b[o];
#pragma unroll
  for (int k = 0; k < 32; k++) {
    float ak = bcastf((k & 1) ? ay : ax, k >> 1);
    float xk = bcastf((k & 1) ? xs.y : xs.x, k >> 1);
    accO = fmaf(ak, Wl[k * 64 + o], accO);
    accO = fmaf(xk, Wr[k * 64 + o], accO);
  }

  // LayerNorm over 64 lanes + ReLU
  float s = accO;
#pragma unroll
  for (int off = 32; off; off >>= 1) s += __shfl_xor(s, off);
  float mu = s * (1.0f / 64.0f);
  float d = accO - mu;
  float v2 = d * d;
#pragma unroll
  for (int off = 32; off; off >>= 1) v2 += __shfl_xor(v2, off);
  float o2 = d * rsqrtf(v2 * (1.0f / 64.0f) + 1e-5f) * g[o] + be[o];
  h1[(size_t)node * 64 + o] = __float2half(fmaxf(o2, 0.0f));
}

// Layer 2 (+ fused layer-3 node part): wave per node. h1 fp16 (32 half2/row).
// Half-wave per row, 2 edges/stride, unroll 4 -> 8 rows in flight; packed
// __hadd2 accumulate. Epilogue: y3 = h2@W_l3, out_self = h2@W_r3 + b3.
__global__ __launch_bounds__(256) void layer2_fused(
    const __half2* __restrict__ h1q, const int* __restrict__ csr,
    const int* __restrict__ offs, const float* __restrict__ Wl,
    const float* __restrict__ Wr, const float* __restrict__ b,
    const float* __restrict__ g, const float* __restrict__ be,
    const float* __restrict__ Wl3, const float* __restrict__ Wr3,
    const float* __restrict__ b3, float* __restrict__ y3,
    float* __restrict__ out) {
  int node = blockIdx.x * 4 + (threadIdx.x >> 6);
  if (node >= N_NODES) return;
  int lane = threadIdx.x & 63;
  int c = lane & 31, half = lane >> 5;

  int end = offs[node];
  int start = (node & 255) ? offs[node - 1] : (node >> 8) * CAP;
  float inv = 1.0f / fmaxf((float)(end - start), 1.0f);

  __half2 A0 = h2zero(), A1 = h2zero(), A2 = h2zero(), A3 = h2zero();
  int slot = start + half;
  for (; slot + 6 < end; slot += 8) {
    int s0 = csr[slot], s1 = csr[slot + 2], s2 = csr[slot + 4], s3 = csr[slot + 6];
    A0 = __hadd2(A0, h1q[(size_t)s0 * 32 + c]);
    A1 = __hadd2(A1, h1q[(size_t)s1 * 32 + c]);
    A2 = __hadd2(A2, h1q[(size_t)s2 * 32 + c]);
    A3 = __hadd2(A3, h1q[(size_t)s3 * 32 + c]);
  }
  if (slot < end) {  // predicated parallel tail (up to 3 rows)
    int i1 = slot + 2, i2 = slot + 4;
    int s0 = csr[slot];
    int s1 = (i1 < end) ? csr[i1] : s0;
    int s2 = (i2 < end) ? csr[i2] : s0;
    __half2 u0 = h1q[(size_t)s0 * 32 + c];
    __half2 u1 = h1q[(size_t)s1 * 32 + c];
    __half2 u2 = h1q[(size_t)s2 * 32 + c];
    A0 = __hadd2(A0, u0);
    A1 = __hadd2(A1, (i1 < end) ? u1 : h2zero());
    A2 = __hadd2(A2, (i2 < end) ? u2 : h2zero());
  }
  __half2 Ah = __hadd2(__hadd2(A0, A1), __hadd2(A2, A3));
  Ah = h2shfl_xor_add(Ah, 32);
  float2 fa = __half22float2(Ah);
  float ax = fa.x * inv, ay = fa.y * inv;

  float2 hs = __half22float2(h1q[(size_t)node * 32 + c]);

  int o = lane;
  float accO = b[o];
#pragma unroll
  for (int k = 0; k < 64; k++) {
    float ak = bcastf((k & 1) ? ay : ax, k >> 1);
    float hk = bcastf((k & 1) ? hs.y : hs.x, k >> 1);
    accO = fmaf(ak, Wl[k * 64 + o], accO);
    accO = fmaf(hk, Wr[k * 64 + o], accO);
  }

  float s = accO;
#pragma unroll
  for (int off = 32; off; off >>= 1) s += __shfl_xor(s, off);
  float mu = s * (1.0f / 64.0f);
  float d = accO - mu;
  float v2 = d * d;
#pragma unroll
  for (int off = 32; off; off >>= 1) v2 += __shfl_xor(v2, off);
  float h2v = fmaxf(d * rsqrtf(v2 * (1.0f / 64.0f) + 1e-5f) * g[o] + be[o], 0.0f);

  // fused layer-3 node part: lane o holds h2[o]
  float t0 = h2v * Wl3[o * 2 + 0];
  float t1 = h2v * Wl3[o * 2 + 1];
  float t2 = h2v * Wr3[o * 2 + 0];
  float t3 = h2v * Wr3[o * 2 + 1];
#pragma unroll
  for (int off = 32; off; off >>= 1) {
    t0 += __shfl_xor(t0, off);
    t1 += __shfl_xor(t1, off);
    t2 += __shfl_xor(t2, off);
    t3 += __shfl_xor(t3, off);
  }
  if (lane == 0) {
    reinterpret_cast<float2*>(y3)[node] = make_float2(t0, t1);
    reinterpret_cast<float2*>(out)[node] = make_float2(t2 + b3[0], t3 + b3[1]);
  }
}

// Layer 3 gather: wave per node, edges strided across lanes, shfl reduce.
// y3 is 800KB -> cache-resident.
__global__ __launch_bounds__(256) void gather3(
    const float* __restrict__ y, const int* __restrict__ csr,
    const int* __restrict__ offs, float* __restrict__ out) {
  int node = blockIdx.x * 4 + (threadIdx.x >> 6);
  if (node >= N_NODES) return;
  int lane = threadIdx.x & 63;

  int end = offs[node];
  int start = (node & 255) ? offs[node - 1] : (node >> 8) * CAP;
  float inv = 1.0f / fmaxf((float)(end - start), 1.0f);

  float s0 = 0.f, s1 = 0.f;
  for (int slot = start + lane; slot < end; slot += 64) {
    float2 v = reinterpret_cast<const float2*>(y)[csr[slot]];
    s0 += v.x;
    s1 += v.y;
  }
#pragma unroll
  for (int off = 32; off; off >>= 1) {
    s0 += __shfl_xor(s0, off);
    s1 += __shfl_xor(s1, off);
  }
  if (lane == 0) {
    out[(size_t)node * 2 + 0] += s0 * inv;
    out[(size_t)node * 2 + 1] += s1 * inv;
  }
}

// ==================== launch ====================

extern "C" void kernel_launch(void* const* d_in, const int* in_sizes, int n_in,
                              void* d_out, int out_size, void* d_ws, size_t ws_size,
                              hipStream_t stream) {
  const float* x = (const float*)d_in[0];
  const int* ei = (const int*)d_in[1];
  const int* src = ei;
  const int* tgt = ei + N_EDGES;
  const float* Wl1 = (const float*)d_in[2];
  const float* Wr1 = (const float*)d_in[3];
  const float* b1 = (const float*)d_in[4];
  const float* g1 = (const float*)d_in[5];
  const float* be1 = (const float*)d_in[6];
  const float* Wl2 = (const float*)d_in[7];
  const float* Wr2 = (const float*)d_in[8];
  const float* b2 = (const float*)d_in[9];
  const float* g2 = (const float*)d_in[10];
  const float* be2 = (const float*)d_in[11];
  const float* Wl3 = (const float*)d_in[12];
  const float* Wr3 = (const float*)d_in[13];
  const float* b3 = (const float*)d_in[14];
  float* out = (float*)d_out;
  char* ws = (char*)d_ws;

  // ---- workspace layout (~42.5 MB) ----
  size_t p = 0;
  auto carve = [&](size_t bytes) {
    size_t r = p;
    p += (bytes + 255) & ~(size_t)255;
    return r;
  };
  size_t cursor_off = carve((size_t)NBK * 4);
  size_t offs_off = carve((size_t)N_NODES * 4);
  size_t csr_off = carve((size_t)NBK * CAP * 4);     // 14.4MB, bucket-padded
  size_t bin_off = carve((size_t)NBK * CAP * 4);     // 14.4MB; xh+y3 alias after sort
  size_t h1_off = carve((size_t)N_NODES * 64 * 2);   // 12.8MB

  int* cursor = (int*)(ws + cursor_off);
  int* offs = (int*)(ws + offs_off);
  int* csr = (int*)(ws + csr_off);
  unsigned int* binned = (unsigned int*)(ws + bin_off);
  __half2* xh = (__half2*)(ws + bin_off);            // aliases binned (dead after sort)
  float* y3 = (float*)(ws + bin_off + (size_t)N_NODES * 32 * 2);  // after xh (6.4MB)
  __half* h1 = (__half*)(ws + h1_off);

  init_cursor<<<(NBK + 255) / 256, 256, 0, stream>>>(cursor);
  bin_scatter<<<NBLK_BIN, 256, 0, stream>>>(src, tgt, cursor, binned);
  bucket_sort<<<NBK, 256, 0, stream>>>(binned, cursor, csr, offs);

  to_half2<<<(N_NODES * 16 + 255) / 256, 256, 0, stream>>>(x, xh, N_NODES * 16);

  layer1_fused<<<(N_NODES + 3) / 4, 256, 0, stream>>>(
      xh, csr, offs, Wl1, Wr1, b1, g1, be1, h1);

  layer2_fused<<<(N_NODES + 3) / 4, 256, 0, stream>>>(
      (const __half2*)h1, csr, offs, Wl2, Wr2, b2, g2, be2, Wl3, Wr3, b3, y3, out);

  gather3<<<(N_NODES + 3) / 4, 256, 0, stream>>>(y3, csr, offs, out);
}

// Round 12
// 309.433 us; speedup vs baseline: 1.9602x; 1.0593x over previous
//
#include <hip/hip_runtime.h>
#include <hip/hip_fp16.h>

#define N_NODES 100000
#define N_EDGES 3200000
#define NBK 391          // ceil(N_NODES / 256) buckets, 256 nodes each
#define CAP 9216         // fixed per-bucket csr capacity (mean 8192, +11 sigma)
#define EPB 8192         // edges per block in binning passes
#define NBLK_BIN 391     // ceil(N_EDGES / EPB)

typedef float v2f __attribute__((ext_vector_type(2)));

// ==================== common helpers ====================

__device__ __forceinline__ int wave_incl_scan_i(int v) {
  int lane = threadIdx.x & 63;
#pragma unroll
  for (int off = 1; off < 64; off <<= 1) {
    int n = __shfl_up(v, off);
    if (lane >= off) v += n;
  }
  return v;
}

// exact f32 broadcast from lane l (uniform l) via v_readlane: no DS-pipe use
__device__ __forceinline__ float bcastf(float v, int l) {
  return __int_as_float(__builtin_amdgcn_readlane(__float_as_int(v), l));
}

__device__ __forceinline__ __half2 h2zero() { return __float2half2_rn(0.0f); }

__device__ __forceinline__ __half2 h2shfl_xor_add(__half2 a, int off) {
  int ai = *reinterpret_cast<int*>(&a);
  int bi = __shfl_xor(ai, off);
  return __hadd2(a, *reinterpret_cast<__half2*>(&bi));
}

// ==================== CSR build: fixed-capacity bucketed sort ====================

__global__ __launch_bounds__(256) void init_cursor(int* __restrict__ cursor) {
  int i = blockIdx.x * 256 + threadIdx.x;
  if (i < NBK) cursor[i] = i * CAP;
}

__global__ __launch_bounds__(256) void bin_scatter(const int* __restrict__ src,
                                                   const int* __restrict__ tgt,
                                                   int* __restrict__ cursor,
                                                   unsigned int* __restrict__ binned) {
  __shared__ int hist[NBK];
  __shared__ int lbase[NBK];
  int t = threadIdx.x;
  for (int i = t; i < NBK; i += 256) hist[i] = 0;
  __syncthreads();
  int e0 = blockIdx.x * EPB;
  int e1 = min(e0 + EPB, N_EDGES);
  for (int e = e0 + t; e < e1; e += 256) atomicAdd(&hist[tgt[e] >> 8], 1);
  __syncthreads();
  for (int i = t; i < NBK; i += 256) {
    int c = hist[i];
    lbase[i] = c ? atomicAdd(&cursor[i], c) : 0;
    hist[i] = 0;  // reuse as local cursor
  }
  __syncthreads();
  for (int e = e0 + t; e < e1; e += 256) {
    int tg = tgt[e];
    int bkt = tg >> 8;
    int lo = atomicAdd(&hist[bkt], 1);
    binned[lbase[bkt] + lo] = (unsigned int)src[e] | ((unsigned int)(tg & 255) << 17);
  }
}

__global__ __launch_bounds__(256) void bucket_sort(const unsigned int* __restrict__ binned,
                                                   const int* __restrict__ cursor,
                                                   int* __restrict__ csr,
                                                   int* __restrict__ offs) {
  __shared__ int deg[256];
  __shared__ int lcur[256];
  __shared__ int wsum[4];
  int b = blockIdx.x;
  int t = threadIdx.x;
  int base = b * CAP;
  int cnt = cursor[b] - base;
  deg[t] = 0;
  __syncthreads();
  for (int i = t; i < cnt; i += 256) atomicAdd(&deg[binned[base + i] >> 17], 1);
  __syncthreads();
  int v = deg[t];
  int inc = wave_incl_scan_i(v);
  int lane = t & 63, wid = t >> 6;
  if (lane == 63) wsum[wid] = inc;
  __syncthreads();
  if (t == 0) {
    int run = 0;
#pragma unroll
    for (int i = 0; i < 4; i++) { int c = wsum[i]; wsum[i] = run; run += c; }
  }
  __syncthreads();
  int incl = inc + wsum[wid];
  lcur[t] = base + incl - v;  // exclusive start
  int node = b * 256 + t;
  if (node < N_NODES) offs[node] = base + incl;  // end position
  __syncthreads();
  for (int i = t; i < cnt; i += 256) {
    unsigned int pv = binned[base + i];
    int pos = atomicAdd(&lcur[pv >> 17], 1);
    csr[pos] = (int)(pv & 0x1FFFFu);
  }
}

// ==================== fp8 conversion (x -> e4m3 packed words) ====================

__global__ __launch_bounds__(256) void to_fp8(const float* __restrict__ x,
                                              unsigned int* __restrict__ xq, int n) {
  int i = blockIdx.x * 256 + threadIdx.x;
  if (i >= n) return;
  float4 v = reinterpret_cast<const float4*>(x)[i];
  int w = 0;
  w = __builtin_amdgcn_cvt_pk_fp8_f32(v.x, v.y, w, false);
  w = __builtin_amdgcn_cvt_pk_fp8_f32(v.z, v.w, w, true);
  xq[i] = (unsigned int)w;
}

// ==================== fused layers ====================

// Layer 1: wave per node. x fp8: row = 8 u32 words (32 ch, 32B). Eighth-wave
// (8 lanes) per row -> 8 rows per instr; unroll 4 -> 32 rows in flight.
// Self term reads original f32 x (full precision). f32 accumulate.
__global__ __launch_bounds__(256) void layer1_fused(
    const unsigned int* __restrict__ xq, const float* __restrict__ xf,
    const int* __restrict__ csr, const int* __restrict__ offs,
    const float* __restrict__ Wl, const float* __restrict__ Wr,
    const float* __restrict__ b, const float* __restrict__ g,
    const float* __restrict__ be, __half* __restrict__ h1) {
  int node = blockIdx.x * 4 + (threadIdx.x >> 6);
  if (node >= N_NODES) return;
  int lane = threadIdx.x & 63;
  int c8 = lane & 7, e8 = lane >> 3;

  int end = offs[node];
  int start = (node & 255) ? offs[node - 1] : (node >> 8) * CAP;
  float inv = 1.0f / fmaxf((float)(end - start), 1.0f);

  v2f a01 = {0.f, 0.f}, a23 = {0.f, 0.f};
  int slot = start + e8;
  for (; slot + 24 < end; slot += 32) {
    unsigned int u0 = xq[(size_t)csr[slot] * 8 + c8];
    unsigned int u1 = xq[(size_t)csr[slot + 8] * 8 + c8];
    unsigned int u2 = xq[(size_t)csr[slot + 16] * 8 + c8];
    unsigned int u3 = xq[(size_t)csr[slot + 24] * 8 + c8];
    a01 += __builtin_amdgcn_cvt_pk_f32_fp8(u0, false);
    a23 += __builtin_amdgcn_cvt_pk_f32_fp8(u0, true);
    a01 += __builtin_amdgcn_cvt_pk_f32_fp8(u1, false);
    a23 += __builtin_amdgcn_cvt_pk_f32_fp8(u1, true);
    a01 += __builtin_amdgcn_cvt_pk_f32_fp8(u2, false);
    a23 += __builtin_amdgcn_cvt_pk_f32_fp8(u2, true);
    a01 += __builtin_amdgcn_cvt_pk_f32_fp8(u3, false);
    a23 += __builtin_amdgcn_cvt_pk_f32_fp8(u3, true);
  }
  if (slot < end) {  // predicated parallel tail (up to 3 rows)
    int i1 = slot + 8, i2 = slot + 16;
    int s0 = csr[slot];
    int s1 = (i1 < end) ? csr[i1] : s0;
    int s2 = (i2 < end) ? csr[i2] : s0;
    unsigned int u0 = xq[(size_t)s0 * 8 + c8];
    unsigned int u1 = xq[(size_t)s1 * 8 + c8];
    unsigned int u2 = xq[(size_t)s2 * 8 + c8];
    float m1 = (i1 < end) ? 1.0f : 0.0f;
    float m2 = (i2 < end) ? 1.0f : 0.0f;
    a01 += __builtin_amdgcn_cvt_pk_f32_fp8(u0, false);
    a23 += __builtin_amdgcn_cvt_pk_f32_fp8(u0, true);
    a01 += m1 * __builtin_amdgcn_cvt_pk_f32_fp8(u1, false);
    a23 += m1 * __builtin_amdgcn_cvt_pk_f32_fp8(u1, true);
    a01 += m2 * __builtin_amdgcn_cvt_pk_f32_fp8(u2, false);
    a23 += m2 * __builtin_amdgcn_cvt_pk_f32_fp8(u2, true);
  }
  // reduce across the 8 row-phases (lane bits 3..5)
#pragma unroll
  for (int off = 8; off < 64; off <<= 1) {
    a01.x += __shfl_xor(a01.x, off);
    a01.y += __shfl_xor(a01.y, off);
    a23.x += __shfl_xor(a23.x, off);
    a23.y += __shfl_xor(a23.y, off);
  }
  a01 *= inv;
  a23 *= inv;

  float xv = xf[(size_t)node * 32 + (lane & 31)];  // self, full f32

  int o = lane;
  float accO = b[o];
#pragma unroll
  for (int k = 0; k < 32; k++) {
    const int j = k & 3;
    float ak = bcastf(j == 0 ? a01.x : j == 1 ? a01.y : j == 2 ? a23.x : a23.y,
                      k >> 2);
    float xk = bcastf(xv, k);
    accO = fmaf(ak, Wl[k * 64 + o], accO);
    accO = fmaf(xk, Wr[k * 64 + o], accO);
  }

  // LayerNorm over 64 lanes + ReLU
  float s = accO;
#pragma unroll
  for (int off = 32; off; off >>= 1) s += __shfl_xor(s, off);
  float mu = s * (1.0f / 64.0f);
  float d = accO - mu;
  float v2 = d * d;
#pragma unroll
  for (int off = 32; off; off >>= 1) v2 += __shfl_xor(v2, off);
  float o2 = d * rsqrtf(v2 * (1.0f / 64.0f) + 1e-5f) * g[o] + be[o];
  h1[(size_t)node * 64 + o] = __float2half(fmaxf(o2, 0.0f));
}

// Layer 2 (+ fused layer-3 node part): wave per node. h1 fp16 (32 half2/row).
// Half-wave per row, 2 edges/stride, unroll 8 -> 16 rows in flight; packed
// __hadd2 accumulate. Epilogue: y3 = h2@W_l3, out_self = h2@W_r3 + b3.
__global__ __launch_bounds__(256) void layer2_fused(
    const __half2* __restrict__ h1q, const int* __restrict__ csr,
    const int* __restrict__ offs, const float* __restrict__ Wl,
    const float* __restrict__ Wr, const float* __restrict__ b,
    const float* __restrict__ g, const float* __restrict__ be,
    const float* __restrict__ Wl3, const float* __restrict__ Wr3,
    const float* __restrict__ b3, float* __restrict__ y3,
    float* __restrict__ out) {
  int node = blockIdx.x * 4 + (threadIdx.x >> 6);
  if (node >= N_NODES) return;
  int lane = threadIdx.x & 63;
  int c = lane & 31, half = lane >> 5;

  int end = offs[node];
  int start = (node & 255) ? offs[node - 1] : (node >> 8) * CAP;
  float inv = 1.0f / fmaxf((float)(end - start), 1.0f);

  __half2 A0 = h2zero(), A1 = h2zero(), A2 = h2zero(), A3 = h2zero();
  __half2 A4 = h2zero(), A5 = h2zero(), A6 = h2zero(), A7 = h2zero();
  int slot = start + half;
  for (; slot + 14 < end; slot += 16) {  // unroll 8: 16 rows in flight
    int s0 = csr[slot], s1 = csr[slot + 2], s2 = csr[slot + 4], s3 = csr[slot + 6];
    int s4 = csr[slot + 8], s5 = csr[slot + 10], s6 = csr[slot + 12], s7 = csr[slot + 14];
    A0 = __hadd2(A0, h1q[(size_t)s0 * 32 + c]);
    A1 = __hadd2(A1, h1q[(size_t)s1 * 32 + c]);
    A2 = __hadd2(A2, h1q[(size_t)s2 * 32 + c]);
    A3 = __hadd2(A3, h1q[(size_t)s3 * 32 + c]);
    A4 = __hadd2(A4, h1q[(size_t)s4 * 32 + c]);
    A5 = __hadd2(A5, h1q[(size_t)s5 * 32 + c]);
    A6 = __hadd2(A6, h1q[(size_t)s6 * 32 + c]);
    A7 = __hadd2(A7, h1q[(size_t)s7 * 32 + c]);
  }
  if (slot + 6 < end) {  // unroll-4 step
    int s0 = csr[slot], s1 = csr[slot + 2], s2 = csr[slot + 4], s3 = csr[slot + 6];
    A0 = __hadd2(A0, h1q[(size_t)s0 * 32 + c]);
    A1 = __hadd2(A1, h1q[(size_t)s1 * 32 + c]);
    A2 = __hadd2(A2, h1q[(size_t)s2 * 32 + c]);
    A3 = __hadd2(A3, h1q[(size_t)s3 * 32 + c]);
    slot += 8;
  }
  if (slot < end) {  // predicated parallel tail (up to 3 rows)
    int i1 = slot + 2, i2 = slot + 4;
    int s0 = csr[slot];
    int s1 = (i1 < end) ? csr[i1] : s0;
    int s2 = (i2 < end) ? csr[i2] : s0;
    __half2 u0 = h1q[(size_t)s0 * 32 + c];
    __half2 u1 = h1q[(size_t)s1 * 32 + c];
    __half2 u2 = h1q[(size_t)s2 * 32 + c];
    A4 = __hadd2(A4, u0);
    A5 = __hadd2(A5, (i1 < end) ? u1 : h2zero());
    A6 = __hadd2(A6, (i2 < end) ? u2 : h2zero());
  }
  __half2 Ah = __hadd2(__hadd2(__hadd2(A0, A1), __hadd2(A2, A3)),
                       __hadd2(__hadd2(A4, A5), __hadd2(A6, A7)));
  Ah = h2shfl_xor_add(Ah, 32);
  float2 fa = __half22float2(Ah);
  float ax = fa.x * inv, ay = fa.y * inv;

  float2 hs = __half22float2(h1q[(size_t)node * 32 + c]);

  int o = lane;
  float accO = b[o];
#pragma unroll
  for (int k = 0; k < 64; k++) {
    float ak = bcastf((k & 1) ? ay : ax, k >> 1);
    float hk = bcastf((k & 1) ? hs.y : hs.x, k >> 1);
    accO = fmaf(ak, Wl[k * 64 + o], accO);
    accO = fmaf(hk, Wr[k * 64 + o], accO);
  }

  float s = accO;
#pragma unroll
  for (int off = 32; off; off >>= 1) s += __shfl_xor(s, off);
  float mu = s * (1.0f / 64.0f);
  float d = accO - mu;
  float v2 = d * d;
#pragma unroll
  for (int off = 32; off; off >>= 1) v2 += __shfl_xor(v2, off);
  float h2v = fmaxf(d * rsqrtf(v2 * (1.0f / 64.0f) + 1e-5f) * g[o] + be[o], 0.0f);

  // fused layer-3 node part: lane o holds h2[o]
  float t0 = h2v * Wl3[o * 2 + 0];
  float t1 = h2v * Wl3[o * 2 + 1];
  float t2 = h2v * Wr3[o * 2 + 0];
  float t3 = h2v * Wr3[o * 2 + 1];
#pragma unroll
  for (int off = 32; off; off >>= 1) {
    t0 += __shfl_xor(t0, off);
    t1 += __shfl_xor(t1, off);
    t2 += __shfl_xor(t2, off);
    t3 += __shfl_xor(t3, off);
  }
  if (lane == 0) {
    reinterpret_cast<float2*>(y3)[node] = make_float2(t0, t1);
    reinterpret_cast<float2*>(out)[node] = make_float2(t2 + b3[0], t3 + b3[1]);
  }
}

// Layer 3 gather: wave per node, edges strided across lanes, shfl reduce.
__global__ __launch_bounds__(256) void gather3(
    const float* __restrict__ y, const int* __restrict__ csr,
    const int* __restrict__ offs, float* __restrict__ out) {
  int node = blockIdx.x * 4 + (threadIdx.x >> 6);
  if (node >= N_NODES) return;
  int lane = threadIdx.x & 63;

  int end = offs[node];
  int start = (node & 255) ? offs[node - 1] : (node >> 8) * CAP;
  float inv = 1.0f / fmaxf((float)(end - start), 1.0f);

  float s0 = 0.f, s1 = 0.f;
  for (int slot = start + lane; slot < end; slot += 64) {
    float2 v = reinterpret_cast<const float2*>(y)[csr[slot]];
    s0 += v.x;
    s1 += v.y;
  }
#pragma unroll
  for (int off = 32; off; off >>= 1) {
    s0 += __shfl_xor(s0, off);
    s1 += __shfl_xor(s1, off);
  }
  if (lane == 0) {
    out[(size_t)node * 2 + 0] += s0 * inv;
    out[(size_t)node * 2 + 1] += s1 * inv;
  }
}

// ==================== launch ====================

extern "C" void kernel_launch(void* const* d_in, const int* in_sizes, int n_in,
                              void* d_out, int out_size, void* d_ws, size_t ws_size,
                              hipStream_t stream) {
  const float* x = (const float*)d_in[0];
  const int* ei = (const int*)d_in[1];
  const int* src = ei;
  const int* tgt = ei + N_EDGES;
  const float* Wl1 = (const float*)d_in[2];
  const float* Wr1 = (const float*)d_in[3];
  const float* b1 = (const float*)d_in[4];
  const float* g1 = (const float*)d_in[5];
  const float* be1 = (const float*)d_in[6];
  const float* Wl2 = (const float*)d_in[7];
  const float* Wr2 = (const float*)d_in[8];
  const float* b2 = (const float*)d_in[9];
  const float* g2 = (const float*)d_in[10];
  const float* be2 = (const float*)d_in[11];
  const float* Wl3 = (const float*)d_in[12];
  const float* Wr3 = (const float*)d_in[13];
  const float* b3 = (const float*)d_in[14];
  float* out = (float*)d_out;
  char* ws = (char*)d_ws;

  // ---- workspace layout (~42.5 MB) ----
  size_t p = 0;
  auto carve = [&](size_t bytes) {
    size_t r = p;
    p += (bytes + 255) & ~(size_t)255;
    return r;
  };
  size_t cursor_off = carve((size_t)NBK * 4);
  size_t offs_off = carve((size_t)N_NODES * 4);
  size_t csr_off = carve((size_t)NBK * CAP * 4);     // 14.4MB, bucket-padded
  size_t bin_off = carve((size_t)NBK * CAP * 4);     // 14.4MB; xq+y3 alias after sort
  size_t h1_off = carve((size_t)N_NODES * 64 * 2);   // 12.8MB

  int* cursor = (int*)(ws + cursor_off);
  int* offs = (int*)(ws + offs_off);
  int* csr = (int*)(ws + csr_off);
  unsigned int* binned = (unsigned int*)(ws + bin_off);
  unsigned int* xq = (unsigned int*)(ws + bin_off);  // 3.2MB, aliases binned (dead)
  float* y3 = (float*)(ws + bin_off + (size_t)N_NODES * 32);  // after xq (3.2MB)
  __half* h1 = (__half*)(ws + h1_off);

  init_cursor<<<(NBK + 255) / 256, 256, 0, stream>>>(cursor);
  bin_scatter<<<NBLK_BIN, 256, 0, stream>>>(src, tgt, cursor, binned);
  bucket_sort<<<NBK, 256, 0, stream>>>(binned, cursor, csr, offs);

  to_fp8<<<(N_NODES * 8 + 255) / 256, 256, 0, stream>>>(x, xq, N_NODES * 8);

  layer1_fused<<<(N_NODES + 3) / 4, 256, 0, stream>>>(
      xq, x, csr, offs, Wl1, Wr1, b1, g1, be1, h1);

  layer2_fused<<<(N_NODES + 3) / 4, 256, 0, stream>>>(
      (const __half2*)h1, csr, offs, Wl2, Wr2, b2, g2, be2, Wl3, Wr3, b3, y3, out);

  gather3<<<(N_NODES + 3) / 4, 256, 0, stream>>>(y3, csr, offs, out);
}